// Round 7
// baseline (317.096 us; speedup 1.0000x reference)
//
#include <hip/hip_runtime.h>
#include <math.h>

// Problem constants (fixed by setup_inputs)
constexpr int Bb  = 2;
constexpr int Nn  = 1280;
constexpr int Cc  = 1024;
constexpr int Hh  = 16;
constexpr int DH  = 64;
constexpr int Ii  = 4096;
constexpr int Tt  = 256;    // text_len
constexpr int BSz = 128;    // block_size
constexpr int L1  = 4;      // len1
constexpr int Mrows = Bb * Nn;  // 2560

typedef __attribute__((ext_vector_type(8))) short short8v;
typedef __attribute__((ext_vector_type(4))) float f32x4;

__device__ __forceinline__ int segof(int n) {
    return n < Tt ? 0 : (n < Tt + L1 * BSz ? 1 : 2);
}
__device__ __forceinline__ unsigned short f2bf(float f) {
    unsigned int u = __float_as_uint(f);
    u += 0x7fffu + ((u >> 16) & 1u);        // RNE
    return (unsigned short)(u >> 16);
}
__device__ __forceinline__ float bf2f(unsigned short h) {
    return __uint_as_float(((unsigned int)h) << 16);
}
// async global->LDS, 16B per lane (dest = wave base + lane*16)
__device__ __forceinline__ void gload16(const void* g, void* l) {
    __builtin_amdgcn_global_load_lds(
        (const __attribute__((address_space(1))) void*)g,
        (__attribute__((address_space(3))) void*)l, 16, 0, 0);
}

// ---------------------------------------------------------------------------
// RMSNorm fp32 -> bf16 out: one block per row, 256 threads, C=1024
// ---------------------------------------------------------------------------
__global__ __launch_bounds__(256)
void rms_bf16(const float* __restrict__ in, const float* __restrict__ w,
              unsigned short* __restrict__ out) {
    int row = blockIdx.x;
    int n   = row % Nn;
    int seg = segof(n);
    const float* x = in + (size_t)row * Cc;
    int t = threadIdx.x;
    float4 xv = reinterpret_cast<const float4*>(x)[t];
    float ss = xv.x * xv.x + xv.y * xv.y + xv.z * xv.z + xv.w * xv.w;
#pragma unroll
    for (int off = 32; off; off >>= 1) ss += __shfl_down(ss, off, 64);
    __shared__ float red[4];
    __shared__ float s_r;
    int lane = t & 63, wid = t >> 6;
    if (lane == 0) red[wid] = ss;
    __syncthreads();
    if (t == 0) s_r = rsqrtf((red[0] + red[1] + red[2] + red[3]) * (1.0f / Cc) + 1e-6f);
    __syncthreads();
    float r = s_r;
    float4 wv = reinterpret_cast<const float4*>(w + (size_t)seg * Cc)[t];
    ushort4 ov;
    ov.x = f2bf(wv.x * xv.x * r);
    ov.y = f2bf(wv.y * xv.y * r);
    ov.z = f2bf(wv.z * xv.z * r);
    ov.w = f2bf(wv.w * xv.w * r);
    *reinterpret_cast<ushort4*>(&out[(size_t)row * Cc + t * 4]) = ov;
}

// ---------------------------------------------------------------------------
// Pack fp32 weights [3][K][Nd] into fragment-linear bf16 layout:
// chunk (kt32, cb, fr, lane) holds 8 bf16: element j =
//   W[seg][kt32*32 + (lane>>4)*8 + j][cb*128 + fr*16 + (lane&15)]
// ---------------------------------------------------------------------------
__global__ __launch_bounds__(256)
void pack_w(const float* __restrict__ W, unsigned short* __restrict__ PB,
            int K, int Nd) {
    size_t idx = (size_t)blockIdx.x * 256 + threadIdx.x;   // chunk id
    size_t cpseg = (size_t)K * Nd / 8;
    int s = (int)(idx / cpseg);
    size_t rm = idx % cpseg;
    int lane = (int)(rm & 63);
    int fr   = (int)((rm >> 6) & 7);
    size_t tile = rm >> 9;                  // kt32*(Nd/128)+cb
    int nct = Nd >> 7;
    int cb = (int)(tile % nct);
    int kt = (int)(tile / nct);
    int col = cb * 128 + fr * 16 + (lane & 15);
    int k0  = kt * 32 + (lane >> 4) * 8;
    const float* src = W + ((size_t)s * K + k0) * Nd + col;
    unsigned short o[8];
#pragma unroll
    for (int j = 0; j < 8; j++) o[j] = f2bf(src[(size_t)j * Nd]);
    short8v v;
#pragma unroll
    for (int j = 0; j < 8; j++) v[j] = (short)o[j];
    *reinterpret_cast<short8v*>(&PB[idx * 8]) = v;
}

// ---------------------------------------------------------------------------
// bf16 MFMA GEMM (m97 structure): 128x128 tile, BK=32, 4 waves (2x2 of
// 64x64 -> 16 MFMA : 8 ds_read_b128), global_load_lds width-16 staging,
// single LDS buffer, 2 barriers per K-step.
// OUTMODE: 0 = f32, 1 = bf16, 2 = bf16 silu(acc)*U epilogue.
// NZ: split-K factor; partial z written at zoff = z*Mrows*Nd (no bias/res).
// ---------------------------------------------------------------------------
template <int OUTMODE, bool BIAS, bool RES, int NZ>
__global__ __launch_bounds__(256)
void gemm128(const unsigned short* __restrict__ A,
             const unsigned short* __restrict__ PB,
             const float* __restrict__ bias, const float* __restrict__ res,
             const unsigned short* __restrict__ U, void* __restrict__ outp,
             int K, int Nd) {
    __shared__ __align__(16) unsigned short lds[8192];   // A 8KB | B 8KB
    int rb = blockIdx.x * 128, cb = blockIdx.y;
    int seg = segof(rb % Nn);
    int tid = threadIdx.x, lane = tid & 63, wid = tid >> 6;
    int wr = wid >> 1, wc = wid & 1;
    int g = lane >> 4, c_ = lane & 15;
    const int nct = Nd >> 7;
    const int Keff = K / NZ;
    const int kz = (NZ > 1) ? blockIdx.z * Keff : 0;
    const unsigned short* PBseg = PB + (size_t)seg * K * Nd;

    // per-thread staging sources (chunk c = tid and tid+256)
    int mf0 = tid >> 6, lc0 = tid & 63;
    const unsigned short* gA0 =
        &A[(size_t)(rb + mf0 * 16 + (lc0 & 15)) * K + kz + (lc0 >> 4) * 8];
    const unsigned short* gA1 = gA0 + (size_t)64 * K;   // mf0+4 -> +64 rows
    const unsigned short* gB0 =
        PBseg + ((((size_t)(kz >> 5) * nct + cb) * 8 + mf0) * 64 + lc0) * 8;
    const unsigned short* gB1 = gB0 + 4 * 64 * 8;       // mf0+4
    const size_t bstep = (size_t)nct * 4096;            // shorts per K-step

    f32x4 acc[4][4];
#pragma unroll
    for (int m = 0; m < 4; m++)
#pragma unroll
        for (int n = 0; n < 4; n++) acc[m][n] = (f32x4){0.f, 0.f, 0.f, 0.f};

    const int nKt = Keff >> 5;
    for (int kt = 0; kt < nKt; ++kt) {
        __syncthreads();                    // prev iteration's ds_reads done
        gload16(gA0 + kt * 32, &lds[(size_t)tid * 8]);
        gload16(gA1 + kt * 32, &lds[(size_t)(tid + 256) * 8]);
        gload16(gB0 + kt * bstep, &lds[4096 + (size_t)tid * 8]);
        gload16(gB1 + kt * bstep, &lds[4096 + (size_t)(tid + 256) * 8]);
        __syncthreads();                    // drains vmcnt (loads landed)
        short8v afr[4], bfr[4];
#pragma unroll
        for (int m = 0; m < 4; m++)
            afr[m] = *reinterpret_cast<short8v*>(&lds[((wr * 4 + m) * 64 + lane) * 8]);
#pragma unroll
        for (int n = 0; n < 4; n++)
            bfr[n] = *reinterpret_cast<short8v*>(&lds[4096 + ((wc * 4 + n) * 64 + lane) * 8]);
#pragma unroll
        for (int m = 0; m < 4; m++)
#pragma unroll
            for (int n = 0; n < 4; n++)
                acc[m][n] = __builtin_amdgcn_mfma_f32_16x16x32_bf16(
                    afr[m], bfr[n], acc[m][n], 0, 0, 0);
    }

    // epilogue: C/D layout col=lane&15, row=(lane>>4)*4+r
    float* outf = (float*)outp;
    unsigned short* outh = (unsigned short*)outp;
    size_t zoff = (NZ > 1) ? (size_t)blockIdx.z * Mrows * Nd : 0;
#pragma unroll
    for (int n = 0; n < 4; n++) {
        int col = cb * 128 + wc * 64 + n * 16 + c_;
        float bvv = BIAS ? bias[(size_t)seg * Nd + col] : 0.f;
#pragma unroll
        for (int m = 0; m < 4; m++) {
#pragma unroll
            for (int r = 0; r < 4; r++) {
                int row = rb + wr * 64 + m * 16 + g * 4 + r;
                float v = acc[m][n][r] + bvv;
                if (RES) v += res[(size_t)row * Nd + col];
                if (OUTMODE == 0) {
                    outf[zoff + (size_t)row * Nd + col] = v;
                } else if (OUTMODE == 1) {
                    outh[zoff + (size_t)row * Nd + col] = f2bf(v);
                } else {
                    float u = bf2f(U[(size_t)row * Nd + col]);
                    float t = v / (1.f + __expf(-v)) * u;
                    outh[(size_t)row * Nd + col] = f2bf(t);
                }
            }
        }
    }
}

// ---------------------------------------------------------------------------
// proj combine: hb = x + bias[seg] + p0 + p1   (fp32 partials)
// ---------------------------------------------------------------------------
__global__ __launch_bounds__(256)
void combine_proj(const float* __restrict__ x, const float* __restrict__ bias,
                  const float* __restrict__ p, float* __restrict__ hb) {
    int i = blockIdx.x * 256 + threadIdx.x;     // float4 index
    int base = i * 4;
    int col = base % Cc;
    int n   = (base / Cc) % Nn;
    int seg = segof(n);
    float4 a = reinterpret_cast<const float4*>(x)[i];
    float4 b = *reinterpret_cast<const float4*>(&bias[(size_t)seg * Cc + col]);
    float4 p0 = reinterpret_cast<const float4*>(p)[i];
    float4 p1 = reinterpret_cast<const float4*>(p)[i + Mrows * Cc / 4];
    float4 r;
    r.x = a.x + b.x + p0.x + p1.x;
    r.y = a.y + b.y + p0.y + p1.y;
    r.z = a.z + b.z + p0.z + p1.z;
    r.w = a.w + b.w + p0.w + p1.w;
    reinterpret_cast<float4*>(hb)[i] = r;
}

// ---------------------------------------------------------------------------
// down combine: out = hb + sum_z bf2f(p_z)    (bf16 partials, NZ=4)
// ---------------------------------------------------------------------------
__global__ __launch_bounds__(256)
void combine_down4(const float* __restrict__ hb,
                   const unsigned short* __restrict__ p,
                   float* __restrict__ out) {
    int i = blockIdx.x * 256 + threadIdx.x;     // 4-elem group
    float4 a = reinterpret_cast<const float4*>(hb)[i];
#pragma unroll
    for (int z = 0; z < 4; z++) {
        ushort4 u = *reinterpret_cast<const ushort4*>(&p[(size_t)z * Mrows * Cc + i * 4]);
        a.x += bf2f(u.x); a.y += bf2f(u.y); a.z += bf2f(u.z); a.w += bf2f(u.w);
    }
    reinterpret_cast<float4*>(out)[i] = a;
}

// ---------------------------------------------------------------------------
// Split qkv(bf16) + per-head q/k RMSNorm + RoPE -> bf16 Q,K,V (bh, n, dh)
// ---------------------------------------------------------------------------
__global__ __launch_bounds__(256)
void split_rope(const unsigned short* __restrict__ qkv,
                const float* __restrict__ qn_w, const float* __restrict__ kn_w,
                const int* __restrict__ pos_ids, const int* __restrict__ tpos_ids,
                unsigned short* __restrict__ Q, unsigned short* __restrict__ K,
                unsigned short* __restrict__ V) {
    int row = blockIdx.x;   // b*N + n
    int b = row / Nn, n = row % Nn;
    int seg = segof(n);
    int lane = threadIdx.x & 63, wid = threadIdx.x >> 6;
    int pos = (n < Tt) ? tpos_ids[n] : pos_ids[n - Tt];
    int j = lane & 31;
    float ang = (float)pos * exp2f(-(float)j * (13.287712379549449f / 32.f));
    float cv = cosf(ang), sv = sinf(ang);
    float qw = qn_w[seg * DH + lane], kw = kn_w[seg * DH + lane];
    for (int h = wid; h < Hh; h += 4) {
        const unsigned short* base = qkv + (size_t)row * (3 * Cc) + h * DH + lane;
        float q = bf2f(base[0]), k = bf2f(base[Cc]), v = bf2f(base[2 * Cc]);
        float qs = q * q, ks = k * k;
#pragma unroll
        for (int off = 32; off; off >>= 1) {
            qs += __shfl_xor(qs, off, 64);
            ks += __shfl_xor(ks, off, 64);
        }
        q = q * rsqrtf(qs * (1.f / DH) + 1e-6f) * qw;
        k = k * rsqrtf(ks * (1.f / DH) + 1e-6f) * kw;
        float qp = __shfl_xor(q, 32, 64);
        float kp = __shfl_xor(k, 32, 64);
        float qo = q * cv + ((lane < 32) ? -qp * sv : qp * sv);
        float ko = k * cv + ((lane < 32) ? -kp * sv : kp * sv);
        size_t oidx = ((size_t)(b * Hh + h) * Nn + n) * DH + lane;
        Q[oidx] = f2bf(qo);
        K[oidx] = f2bf(ko);
        V[oidx] = f2bf(v);
    }
}

// ---------------------------------------------------------------------------
// MFMA flash attention (unchanged — verified)
// ---------------------------------------------------------------------------
__global__ __launch_bounds__(256)
void attn_mfma(const unsigned short* __restrict__ Qg,
               const unsigned short* __restrict__ Kg,
               const unsigned short* __restrict__ Vg,
               unsigned short* __restrict__ O) {
    __shared__ __align__(16) unsigned short k_lds[64 * 64];   // 8 KB
    __shared__ __align__(16) unsigned short vt_lds[64 * 64];  // 8 KB
    __shared__ __align__(16) unsigned short p_lds[4][16 * 64];// 8 KB

    int qt = blockIdx.x;
    int bh = blockIdx.y;
    int b = bh >> 4, h = bh & 15;
    int tid = threadIdx.x, lane = tid & 63, wid = tid >> 6;
    int g = lane >> 4, c = lane & 15;

    const size_t headoff = (size_t)bh * Nn * DH;
    int q0 = qt * 64;
    bool qtext = q0 < Tt;
    int qb = qtext ? 0 : (q0 - Tt) / BSz;

    int qrow_frag = q0 + wid * 16 + c;
    short8v aq[2];
#pragma unroll
    for (int kb = 0; kb < 2; kb++)
        aq[kb] = *reinterpret_cast<const short8v*>(
            &Qg[headoff + (size_t)qrow_frag * DH + kb * 32 + g * 8]);

    unsigned short* pbuf = &p_lds[wid][0];

    f32x4 o_[4];
#pragma unroll
    for (int nb = 0; nb < 4; nb++) o_[nb] = (f32x4){0.f, 0.f, 0.f, 0.f};
    float m_[4] = {-3.4e38f, -3.4e38f, -3.4e38f, -3.4e38f};
    float l_[4] = {0.f, 0.f, 0.f, 0.f};

    int tr = tid >> 2, tc = tid & 3;

    for (int kt = 0; kt < Nn / 64; kt++) {
        int kbase = kt * 64;
        bool vis, diag = false;
        if (qtext) {
            vis = (kbase <= q0);
            diag = (kbase == q0);
        } else if (kbase < Tt) {
            vis = true;
        } else {
            int kb = (kbase - Tt) / BSz;
            vis = (qb < L1) ? (kb <= qb)
                            : ((kb < L1 && qb - L1 > kb) || kb == qb);
        }
        if (!vis) continue;

        __syncthreads();
        {
            const unsigned short* ks = &Kg[headoff + (size_t)(kbase + tr) * DH];
            const unsigned short* vs = &Vg[headoff + (size_t)(kbase + tr) * DH];
#pragma unroll
            for (int i = 0; i < 2; i++) {
                int ch = tc + i * 4;
                short8v kv = *reinterpret_cast<const short8v*>(ks + ch * 8);
                int byte = (tr * 128 + ch * 16) ^ ((tr & 7) << 4);
                *reinterpret_cast<short8v*>((char*)k_lds + byte) = kv;
                short8v vv = *reinterpret_cast<const short8v*>(vs + ch * 8);
#pragma unroll
                for (int j = 0; j < 8; j++) {
                    int dh = ch * 8 + j;
                    int vbyte = (dh * 128 + tr * 2) ^ ((dh & 7) << 4);
                    *reinterpret_cast<unsigned short*>((char*)vt_lds + vbyte) =
                        (unsigned short)vv[j];
                }
            }
        }
        __syncthreads();

        f32x4 s_[4];
#pragma unroll
        for (int nb = 0; nb < 4; nb++) s_[nb] = (f32x4){0.f, 0.f, 0.f, 0.f};
#pragma unroll
        for (int nb = 0; nb < 4; nb++) {
            int kil = nb * 16 + c;
#pragma unroll
            for (int kb = 0; kb < 2; kb++) {
                int byte = (kil * 128 + kb * 64 + g * 16) ^ ((kil & 7) << 4);
                short8v bk = *reinterpret_cast<short8v*>((char*)k_lds + byte);
                s_[nb] = __builtin_amdgcn_mfma_f32_16x16x32_bf16(aq[kb], bk, s_[nb], 0, 0, 0);
            }
        }
#pragma unroll
        for (int nb = 0; nb < 4; nb++) {
#pragma unroll
            for (int r = 0; r < 4; r++) {
                float sv = s_[nb][r] * 0.125f;
                if (diag) {
                    int qrl = wid * 16 + g * 4 + r;
                    int kcl = nb * 16 + c;
                    if (qrl < kcl) sv = -3.4e38f;
                }
                s_[nb][r] = sv;
            }
        }
#pragma unroll
        for (int r = 0; r < 4; r++) {
            float mx = fmaxf(fmaxf(s_[0][r], s_[1][r]), fmaxf(s_[2][r], s_[3][r]));
#pragma unroll
            for (int off = 1; off <= 8; off <<= 1)
                mx = fmaxf(mx, __shfl_xor(mx, off, 64));
            float mn = fmaxf(m_[r], mx);
            float es = __expf(m_[r] - mn);
            m_[r] = mn;
            float pv[4];
            float rs = 0.f;
#pragma unroll
            for (int nb = 0; nb < 4; nb++) {
                pv[nb] = __expf(s_[nb][r] - mn);
                rs += pv[nb];
            }
#pragma unroll
            for (int off = 1; off <= 8; off <<= 1)
                rs += __shfl_xor(rs, off, 64);
            l_[r] = l_[r] * es + rs;
#pragma unroll
            for (int nb = 0; nb < 4; nb++) o_[nb][r] *= es;
            int qrl = g * 4 + r;
            int swz = (qrl & 7) << 4;
#pragma unroll
            for (int nb = 0; nb < 4; nb++) {
                int byte = (qrl * 128 + (nb * 16 + c) * 2) ^ swz;
                *reinterpret_cast<unsigned short*>((char*)pbuf + byte) = f2bf(pv[nb]);
            }
        }
        short8v aP[2];
#pragma unroll
        for (int kb = 0; kb < 2; kb++) {
            int byte = (c * 128 + kb * 64 + g * 16) ^ ((c & 7) << 4);
            aP[kb] = *reinterpret_cast<short8v*>((char*)pbuf + byte);
        }
#pragma unroll
        for (int nb = 0; nb < 4; nb++) {
            int dh = nb * 16 + c;
#pragma unroll
            for (int kb = 0; kb < 2; kb++) {
                int byte = (dh * 128 + kb * 64 + g * 16) ^ ((dh & 7) << 4);
                short8v bv = *reinterpret_cast<short8v*>((char*)vt_lds + byte);
                o_[nb] = __builtin_amdgcn_mfma_f32_16x16x32_bf16(aP[kb], bv, o_[nb], 0, 0, 0);
            }
        }
    }

    float inv_[4];
#pragma unroll
    for (int r = 0; r < 4; r++) inv_[r] = 1.f / l_[r];
#pragma unroll
    for (int nb = 0; nb < 4; nb++) {
        int col = h * DH + nb * 16 + c;
#pragma unroll
        for (int r = 0; r < 4; r++) {
            int row = q0 + wid * 16 + g * 4 + r;
            O[((size_t)b * Nn + row) * Cc + col] = f2bf(o_[nb][r] * inv_[r]);
        }
    }
}

// ---------------------------------------------------------------------------
// kernel_launch
// ---------------------------------------------------------------------------
extern "C" void kernel_launch(void* const* d_in, const int* in_sizes, int n_in,
                              void* d_out, int out_size, void* d_ws, size_t ws_size,
                              hipStream_t stream) {
    const float* x        = (const float*)d_in[0];
    const int*   pos_ids  = (const int*)d_in[1];
    const int*   tpos_ids = (const int*)d_in[2];
    const float* qkv_w    = (const float*)d_in[3];
    const float* qkv_b    = (const float*)d_in[4];
    const float* proj_w   = (const float*)d_in[5];
    const float* proj_b   = (const float*)d_in[6];
    const float* qn_w     = (const float*)d_in[7];
    const float* kn_w     = (const float*)d_in[8];
    const float* ln1_w    = (const float*)d_in[9];
    const float* ln2_w    = (const float*)d_in[10];
    const float* gate_w   = (const float*)d_in[11];
    const float* up_w     = (const float*)d_in[12];
    const float* down_w   = (const float*)d_in[13];
    float* out = (float*)d_out;
    char*  wsb = (char*)d_ws;

    // workspace regions (bytes)
    unsigned short* Wp   = (unsigned short*)(wsb);              // 25.2 MB packed weights
    unsigned short* P1   = (unsigned short*)(wsb + 25165824);   // qkv / proj-partials / t
    unsigned short* P2   = (unsigned short*)(wsb + 46137344);   // QKV bf16 / u / down partials
    unsigned short* P3   = (unsigned short*)(wsb + 67108864);   // xn/o/y bf16 (5.24 MB)
    float*          hb   = (float*)(wsb + 72351744);            // 10.49 MB fp32
    unsigned short* Qbf  = P2;
    unsigned short* Kbf  = P2 + 2621440;
    unsigned short* Vbf  = P2 + 5242880;

    // 1. xn = RMS(x, ln1) -> bf16
    rms_bf16<<<Mrows, 256, 0, stream>>>(x, ln1_w, P3);
    // 2. pack qkv weights; qkv GEMM -> bf16 (480 blocks)
    pack_w<<<4608, 256, 0, stream>>>(qkv_w, Wp, Cc, 3 * Cc);
    gemm128<1, true, false, 1><<<dim3(Mrows / 128, 24), 256, 0, stream>>>(
        P3, Wp, qkv_b, nullptr, nullptr, P1, Cc, 3 * Cc);
    // 3. split + q/k RMS + RoPE (bf16)
    split_rope<<<Mrows, 256, 0, stream>>>(P1, qn_w, kn_w, pos_ids, tpos_ids,
                                          Qbf, Kbf, Vbf);
    // 4. attention -> obf (bf16, (B,N,C))
    attn_mfma<<<dim3(Nn / 64, Bb * Hh), 256, 0, stream>>>(Qbf, Kbf, Vbf, P3);
    // 5. proj split-K=2 -> fp32 partials in P1; combine: hb = x + bias + p0 + p1
    pack_w<<<1536, 256, 0, stream>>>(proj_w, Wp, Cc, Cc);
    gemm128<0, false, false, 2><<<dim3(Mrows / 128, 8, 2), 256, 0, stream>>>(
        P3, Wp, nullptr, nullptr, nullptr, (float*)P1, Cc, Cc);
    combine_proj<<<Mrows * Cc / 1024, 256, 0, stream>>>(x, proj_b, (float*)P1, hb);
    // 6. y = RMS(h, ln2) -> bf16
    rms_bf16<<<Mrows, 256, 0, stream>>>(hb, ln2_w, P3);
    // 7. u = y @ up_w -> bf16 (P2)   (640 blocks)
    pack_w<<<6144, 256, 0, stream>>>(up_w, Wp, Cc, Ii);
    gemm128<1, false, false, 1><<<dim3(Mrows / 128, 32), 256, 0, stream>>>(
        P3, Wp, nullptr, nullptr, nullptr, P2, Cc, Ii);
    // 8. t = silu(y @ gate_w) * u -> bf16 (P1)
    pack_w<<<6144, 256, 0, stream>>>(gate_w, Wp, Cc, Ii);
    gemm128<2, false, false, 1><<<dim3(Mrows / 128, 32), 256, 0, stream>>>(
        P3, Wp, nullptr, nullptr, P2, P1, Cc, Ii);
    // 9. down split-K=4 -> bf16 partials in P2; out = hb + sum(p_z)
    pack_w<<<6144, 256, 0, stream>>>(down_w, Wp, Ii, Cc);
    gemm128<1, false, false, 4><<<dim3(Mrows / 128, 8, 4), 256, 0, stream>>>(
        P1, Wp, nullptr, nullptr, nullptr, P2, Ii, Cc);
    combine_down4<<<Mrows * Cc / 1024, 256, 0, stream>>>(hb, P2, out);
}

// Round 8
// 291.910 us; speedup vs baseline: 1.0863x; 1.0863x over previous
//
#include <hip/hip_runtime.h>
#include <math.h>

// Problem constants (fixed by setup_inputs)
constexpr int Bb  = 2;
constexpr int Nn  = 1280;
constexpr int Cc  = 1024;
constexpr int Hh  = 16;
constexpr int DH  = 64;
constexpr int Ii  = 4096;
constexpr int Tt  = 256;    // text_len
constexpr int BSz = 128;    // block_size
constexpr int L1  = 4;      // len1
constexpr int Mrows = Bb * Nn;  // 2560

typedef __attribute__((ext_vector_type(8))) short short8v;
typedef __attribute__((ext_vector_type(4))) float f32x4;

__device__ __forceinline__ int segof(int n) {
    return n < Tt ? 0 : (n < Tt + L1 * BSz ? 1 : 2);
}
__device__ __forceinline__ unsigned short f2bf(float f) {
    unsigned int u = __float_as_uint(f);
    u += 0x7fffu + ((u >> 16) & 1u);        // RNE
    return (unsigned short)(u >> 16);
}
__device__ __forceinline__ float bf2f(unsigned short h) {
    return __uint_as_float(((unsigned int)h) << 16);
}
// async global->LDS, 16B per lane (dest = wave base + lane*16)
__device__ __forceinline__ void gload16(const void* g, void* l) {
    __builtin_amdgcn_global_load_lds(
        (const __attribute__((address_space(1))) void*)g,
        (__attribute__((address_space(3))) void*)l, 16, 0, 0);
}

// ---------------------------------------------------------------------------
// RMSNorm fp32 -> bf16 out: one block per row, 256 threads, C=1024
// ---------------------------------------------------------------------------
__global__ __launch_bounds__(256)
void rms_bf16(const float* __restrict__ in, const float* __restrict__ w,
              unsigned short* __restrict__ out) {
    int row = blockIdx.x;
    int n   = row % Nn;
    int seg = segof(n);
    const float* x = in + (size_t)row * Cc;
    int t = threadIdx.x;
    float4 xv = reinterpret_cast<const float4*>(x)[t];
    float ss = xv.x * xv.x + xv.y * xv.y + xv.z * xv.z + xv.w * xv.w;
#pragma unroll
    for (int off = 32; off; off >>= 1) ss += __shfl_down(ss, off, 64);
    __shared__ float red[4];
    __shared__ float s_r;
    int lane = t & 63, wid = t >> 6;
    if (lane == 0) red[wid] = ss;
    __syncthreads();
    if (t == 0) s_r = rsqrtf((red[0] + red[1] + red[2] + red[3]) * (1.0f / Cc) + 1e-6f);
    __syncthreads();
    float r = s_r;
    float4 wv = reinterpret_cast<const float4*>(w + (size_t)seg * Cc)[t];
    ushort4 ov;
    ov.x = f2bf(wv.x * xv.x * r);
    ov.y = f2bf(wv.y * xv.y * r);
    ov.z = f2bf(wv.z * xv.z * r);
    ov.w = f2bf(wv.w * xv.w * r);
    *reinterpret_cast<ushort4*>(&out[(size_t)row * Cc + t * 4]) = ov;
}

// ---------------------------------------------------------------------------
// Pack fp32 weights [3][K][Nd] into fragment-linear bf16 layout:
// chunk (kt32, cb, fr, lane) holds 8 bf16: element j =
//   W[seg][kt32*32 + (lane>>4)*8 + j][cb*128 + fr*16 + (lane&15)]
// ---------------------------------------------------------------------------
__global__ __launch_bounds__(256)
void pack_w(const float* __restrict__ W, unsigned short* __restrict__ PB,
            int K, int Nd) {
    size_t idx = (size_t)blockIdx.x * 256 + threadIdx.x;   // chunk id
    size_t cpseg = (size_t)K * Nd / 8;
    int s = (int)(idx / cpseg);
    size_t rm = idx % cpseg;
    int lane = (int)(rm & 63);
    int fr   = (int)((rm >> 6) & 7);
    size_t tile = rm >> 9;                  // kt32*(Nd/128)+cb
    int nct = Nd >> 7;
    int cb = (int)(tile % nct);
    int kt = (int)(tile / nct);
    int col = cb * 128 + fr * 16 + (lane & 15);
    int k0  = kt * 32 + (lane >> 4) * 8;
    const float* src = W + ((size_t)s * K + k0) * Nd + col;
    unsigned short o[8];
#pragma unroll
    for (int j = 0; j < 8; j++) o[j] = f2bf(src[(size_t)j * Nd]);
    short8v v;
#pragma unroll
    for (int j = 0; j < 8; j++) v[j] = (short)o[j];
    *reinterpret_cast<short8v*>(&PB[idx * 8]) = v;
}

// ---------------------------------------------------------------------------
// bf16 MFMA GEMM v3: 128x128 tile, BK=32, 4 waves (2x2 of 64x64),
// DOUBLE-BUFFERED LDS + 2-phase prefetch via global_load_lds:
//   per K-step: issue next tile's 4 gload16 -> ds_read current frags ->
//   16 MFMA -> ONE __syncthreads (implicit vmcnt(0) lands after the
//   compute window, hiding load latency; T3 minimum-2-phase recipe).
// XCD-aware bijective block swizzle (all launch grids are %8 == 0).
// OUTMODE: 0 = f32, 1 = bf16, 2 = bf16 silu(acc)*U epilogue.
// NZ: split-K factor; partial z written at zoff = z*Mrows*Nd (no bias/res).
// ---------------------------------------------------------------------------
template <int OUTMODE, bool BIAS, bool RES, int NZ>
__global__ __launch_bounds__(256)
void gemm128(const unsigned short* __restrict__ A,
             const unsigned short* __restrict__ PB,
             const float* __restrict__ bias, const float* __restrict__ res,
             const unsigned short* __restrict__ U, void* __restrict__ outp,
             int K, int Nd) {
    __shared__ __align__(16) unsigned short lds[16384];  // 2 bufs x (A 8KB | B 8KB)

    // XCD swizzle: consecutive hardware blocks go to different XCDs; remap so
    // each XCD owns a contiguous chunk of (col-panel-major) work items.
    int bx = blockIdx.x, by = blockIdx.y, bz = (NZ > 1) ? blockIdx.z : 0;
    {
        int gx = gridDim.x, gy = gridDim.y, gz = (NZ > 1) ? gridDim.z : 1;
        int nwg = gx * gy * gz;               // always % 8 == 0 here
        int lin = bx + gx * (by + gy * bz);
        int cpx = nwg >> 3;
        int swz = (lin & 7) * cpx + (lin >> 3);
        bx = swz % gx; swz /= gx;
        by = swz % gy; bz = swz / gy;
    }
    int rb = bx * 128, cb = by;
    int seg = segof(rb % Nn);
    int tid = threadIdx.x, lane = tid & 63, wid = tid >> 6;
    int wr = wid >> 1, wc = wid & 1;
    int g = lane >> 4, c_ = lane & 15;
    const int nct = Nd >> 7;
    const int Keff = K / NZ;
    const int kz = bz * Keff;
    const unsigned short* PBseg = PB + (size_t)seg * K * Nd;

    // per-thread staging sources (chunk c = tid and tid+256)
    int mf0 = tid >> 6, lc0 = tid & 63;
    const unsigned short* gA0 =
        &A[(size_t)(rb + mf0 * 16 + (lc0 & 15)) * K + kz + (lc0 >> 4) * 8];
    const unsigned short* gA1 = gA0 + (size_t)64 * K;   // mf0+4 -> +64 rows
    const unsigned short* gB0 =
        PBseg + ((((size_t)(kz >> 5) * nct + cb) * 8 + mf0) * 64 + lc0) * 8;
    const unsigned short* gB1 = gB0 + 2048;             // mf0+4
    const size_t bstep = (size_t)nct * 4096;            // shorts per K-step

    f32x4 acc[4][4];
#pragma unroll
    for (int m = 0; m < 4; m++)
#pragma unroll
        for (int n = 0; n < 4; n++) acc[m][n] = (f32x4){0.f, 0.f, 0.f, 0.f};

    const int nKt = Keff >> 5;

    // prologue: stage tile 0 into buf 0, drain, then 2-phase loop
    gload16(gA0, &lds[(size_t)tid * 8]);
    gload16(gA1, &lds[(size_t)(tid + 256) * 8]);
    gload16(gB0, &lds[4096 + (size_t)tid * 8]);
    gload16(gB1, &lds[4096 + (size_t)(tid + 256) * 8]);
    __syncthreads();

    int cur = 0;
    for (int kt = 0; kt < nKt; ++kt) {
        if (kt + 1 < nKt) {                 // issue NEXT tile first (prefetch)
            int bo = (cur ^ 1) * 8192;
            gload16(gA0 + (kt + 1) * 32, &lds[bo + (size_t)tid * 8]);
            gload16(gA1 + (kt + 1) * 32, &lds[bo + (size_t)(tid + 256) * 8]);
            gload16(gB0 + (kt + 1) * bstep, &lds[bo + 4096 + (size_t)tid * 8]);
            gload16(gB1 + (kt + 1) * bstep, &lds[bo + 4096 + (size_t)(tid + 256) * 8]);
        }
        int bo = cur * 8192;
        short8v afr[4], bfr[4];
#pragma unroll
        for (int m = 0; m < 4; m++)
            afr[m] = *reinterpret_cast<short8v*>(&lds[bo + ((wr * 4 + m) * 64 + lane) * 8]);
#pragma unroll
        for (int n = 0; n < 4; n++)
            bfr[n] = *reinterpret_cast<short8v*>(&lds[bo + 4096 + ((wc * 4 + n) * 64 + lane) * 8]);
#pragma unroll
        for (int m = 0; m < 4; m++)
#pragma unroll
            for (int n = 0; n < 4; n++)
                acc[m][n] = __builtin_amdgcn_mfma_f32_16x16x32_bf16(
                    afr[m], bfr[n], acc[m][n], 0, 0, 0);
        __syncthreads();                    // vmcnt(0)+barrier: next buf ready
        cur ^= 1;
    }

    // epilogue: C/D layout col=lane&15, row=(lane>>4)*4+r
    float* outf = (float*)outp;
    unsigned short* outh = (unsigned short*)outp;
    size_t zoff = (NZ > 1) ? (size_t)bz * Mrows * Nd : 0;
#pragma unroll
    for (int n = 0; n < 4; n++) {
        int col = cb * 128 + wc * 64 + n * 16 + c_;
        float bvv = BIAS ? bias[(size_t)seg * Nd + col] : 0.f;
#pragma unroll
        for (int m = 0; m < 4; m++) {
#pragma unroll
            for (int r = 0; r < 4; r++) {
                int row = rb + wr * 64 + m * 16 + g * 4 + r;
                float v = acc[m][n][r] + bvv;
                if (RES) v += res[(size_t)row * Nd + col];
                if (OUTMODE == 0) {
                    outf[zoff + (size_t)row * Nd + col] = v;
                } else if (OUTMODE == 1) {
                    outh[zoff + (size_t)row * Nd + col] = f2bf(v);
                } else {
                    float u = bf2f(U[(size_t)row * Nd + col]);
                    float t = v / (1.f + __expf(-v)) * u;
                    outh[(size_t)row * Nd + col] = f2bf(t);
                }
            }
        }
    }
}

// ---------------------------------------------------------------------------
// proj combine: hb = x + bias[seg] + p0 + p1   (fp32 partials)
// ---------------------------------------------------------------------------
__global__ __launch_bounds__(256)
void combine_proj(const float* __restrict__ x, const float* __restrict__ bias,
                  const float* __restrict__ p, float* __restrict__ hb) {
    int i = blockIdx.x * 256 + threadIdx.x;     // float4 index
    int base = i * 4;
    int col = base % Cc;
    int n   = (base / Cc) % Nn;
    int seg = segof(n);
    float4 a = reinterpret_cast<const float4*>(x)[i];
    float4 b = *reinterpret_cast<const float4*>(&bias[(size_t)seg * Cc + col]);
    float4 p0 = reinterpret_cast<const float4*>(p)[i];
    float4 p1 = reinterpret_cast<const float4*>(p)[i + Mrows * Cc / 4];
    float4 r;
    r.x = a.x + b.x + p0.x + p1.x;
    r.y = a.y + b.y + p0.y + p1.y;
    r.z = a.z + b.z + p0.z + p1.z;
    r.w = a.w + b.w + p0.w + p1.w;
    reinterpret_cast<float4*>(hb)[i] = r;
}

// ---------------------------------------------------------------------------
// down combine: out = hb + sum_z bf2f(p_z)    (bf16 partials, NZ=4)
// ---------------------------------------------------------------------------
__global__ __launch_bounds__(256)
void combine_down4(const float* __restrict__ hb,
                   const unsigned short* __restrict__ p,
                   float* __restrict__ out) {
    int i = blockIdx.x * 256 + threadIdx.x;     // 4-elem group
    float4 a = reinterpret_cast<const float4*>(hb)[i];
#pragma unroll
    for (int z = 0; z < 4; z++) {
        ushort4 u = *reinterpret_cast<const ushort4*>(&p[(size_t)z * Mrows * Cc + i * 4]);
        a.x += bf2f(u.x); a.y += bf2f(u.y); a.z += bf2f(u.z); a.w += bf2f(u.w);
    }
    reinterpret_cast<float4*>(out)[i] = a;
}

// ---------------------------------------------------------------------------
// Split qkv(bf16) + per-head q/k RMSNorm + RoPE -> bf16 Q,K,V (bh, n, dh)
// ---------------------------------------------------------------------------
__global__ __launch_bounds__(256)
void split_rope(const unsigned short* __restrict__ qkv,
                const float* __restrict__ qn_w, const float* __restrict__ kn_w,
                const int* __restrict__ pos_ids, const int* __restrict__ tpos_ids,
                unsigned short* __restrict__ Q, unsigned short* __restrict__ K,
                unsigned short* __restrict__ V) {
    int row = blockIdx.x;   // b*N + n
    int b = row / Nn, n = row % Nn;
    int seg = segof(n);
    int lane = threadIdx.x & 63, wid = threadIdx.x >> 6;
    int pos = (n < Tt) ? tpos_ids[n] : pos_ids[n - Tt];
    int j = lane & 31;
    float ang = (float)pos * exp2f(-(float)j * (13.287712379549449f / 32.f));
    float cv = cosf(ang), sv = sinf(ang);
    float qw = qn_w[seg * DH + lane], kw = kn_w[seg * DH + lane];
    for (int h = wid; h < Hh; h += 4) {
        const unsigned short* base = qkv + (size_t)row * (3 * Cc) + h * DH + lane;
        float q = bf2f(base[0]), k = bf2f(base[Cc]), v = bf2f(base[2 * Cc]);
        float qs = q * q, ks = k * k;
#pragma unroll
        for (int off = 32; off; off >>= 1) {
            qs += __shfl_xor(qs, off, 64);
            ks += __shfl_xor(ks, off, 64);
        }
        q = q * rsqrtf(qs * (1.f / DH) + 1e-6f) * qw;
        k = k * rsqrtf(ks * (1.f / DH) + 1e-6f) * kw;
        float qp = __shfl_xor(q, 32, 64);
        float kp = __shfl_xor(k, 32, 64);
        float qo = q * cv + ((lane < 32) ? -qp * sv : qp * sv);
        float ko = k * cv + ((lane < 32) ? -kp * sv : kp * sv);
        size_t oidx = ((size_t)(b * Hh + h) * Nn + n) * DH + lane;
        Q[oidx] = f2bf(qo);
        K[oidx] = f2bf(ko);
        V[oidx] = f2bf(v);
    }
}

// ---------------------------------------------------------------------------
// MFMA flash attention (unchanged — verified)
// ---------------------------------------------------------------------------
__global__ __launch_bounds__(256)
void attn_mfma(const unsigned short* __restrict__ Qg,
               const unsigned short* __restrict__ Kg,
               const unsigned short* __restrict__ Vg,
               unsigned short* __restrict__ O) {
    __shared__ __align__(16) unsigned short k_lds[64 * 64];   // 8 KB
    __shared__ __align__(16) unsigned short vt_lds[64 * 64];  // 8 KB
    __shared__ __align__(16) unsigned short p_lds[4][16 * 64];// 8 KB

    int qt = blockIdx.x;
    int bh = blockIdx.y;
    int b = bh >> 4, h = bh & 15;
    int tid = threadIdx.x, lane = tid & 63, wid = tid >> 6;
    int g = lane >> 4, c = lane & 15;

    const size_t headoff = (size_t)bh * Nn * DH;
    int q0 = qt * 64;
    bool qtext = q0 < Tt;
    int qb = qtext ? 0 : (q0 - Tt) / BSz;

    int qrow_frag = q0 + wid * 16 + c;
    short8v aq[2];
#pragma unroll
    for (int kb = 0; kb < 2; kb++)
        aq[kb] = *reinterpret_cast<const short8v*>(
            &Qg[headoff + (size_t)qrow_frag * DH + kb * 32 + g * 8]);

    unsigned short* pbuf = &p_lds[wid][0];

    f32x4 o_[4];
#pragma unroll
    for (int nb = 0; nb < 4; nb++) o_[nb] = (f32x4){0.f, 0.f, 0.f, 0.f};
    float m_[4] = {-3.4e38f, -3.4e38f, -3.4e38f, -3.4e38f};
    float l_[4] = {0.f, 0.f, 0.f, 0.f};

    int tr = tid >> 2, tc = tid & 3;

    for (int kt = 0; kt < Nn / 64; kt++) {
        int kbase = kt * 64;
        bool vis, diag = false;
        if (qtext) {
            vis = (kbase <= q0);
            diag = (kbase == q0);
        } else if (kbase < Tt) {
            vis = true;
        } else {
            int kb = (kbase - Tt) / BSz;
            vis = (qb < L1) ? (kb <= qb)
                            : ((kb < L1 && qb - L1 > kb) || kb == qb);
        }
        if (!vis) continue;

        __syncthreads();
        {
            const unsigned short* ks = &Kg[headoff + (size_t)(kbase + tr) * DH];
            const unsigned short* vs = &Vg[headoff + (size_t)(kbase + tr) * DH];
#pragma unroll
            for (int i = 0; i < 2; i++) {
                int ch = tc + i * 4;
                short8v kv = *reinterpret_cast<const short8v*>(ks + ch * 8);
                int byte = (tr * 128 + ch * 16) ^ ((tr & 7) << 4);
                *reinterpret_cast<short8v*>((char*)k_lds + byte) = kv;
                short8v vv = *reinterpret_cast<const short8v*>(vs + ch * 8);
#pragma unroll
                for (int j = 0; j < 8; j++) {
                    int dh = ch * 8 + j;
                    int vbyte = (dh * 128 + tr * 2) ^ ((dh & 7) << 4);
                    *reinterpret_cast<unsigned short*>((char*)vt_lds + vbyte) =
                        (unsigned short)vv[j];
                }
            }
        }
        __syncthreads();

        f32x4 s_[4];
#pragma unroll
        for (int nb = 0; nb < 4; nb++) s_[nb] = (f32x4){0.f, 0.f, 0.f, 0.f};
#pragma unroll
        for (int nb = 0; nb < 4; nb++) {
            int kil = nb * 16 + c;
#pragma unroll
            for (int kb = 0; kb < 2; kb++) {
                int byte = (kil * 128 + kb * 64 + g * 16) ^ ((kil & 7) << 4);
                short8v bk = *reinterpret_cast<short8v*>((char*)k_lds + byte);
                s_[nb] = __builtin_amdgcn_mfma_f32_16x16x32_bf16(aq[kb], bk, s_[nb], 0, 0, 0);
            }
        }
#pragma unroll
        for (int nb = 0; nb < 4; nb++) {
#pragma unroll
            for (int r = 0; r < 4; r++) {
                float sv = s_[nb][r] * 0.125f;
                if (diag) {
                    int qrl = wid * 16 + g * 4 + r;
                    int kcl = nb * 16 + c;
                    if (qrl < kcl) sv = -3.4e38f;
                }
                s_[nb][r] = sv;
            }
        }
#pragma unroll
        for (int r = 0; r < 4; r++) {
            float mx = fmaxf(fmaxf(s_[0][r], s_[1][r]), fmaxf(s_[2][r], s_[3][r]));
#pragma unroll
            for (int off = 1; off <= 8; off <<= 1)
                mx = fmaxf(mx, __shfl_xor(mx, off, 64));
            float mn = fmaxf(m_[r], mx);
            float es = __expf(m_[r] - mn);
            m_[r] = mn;
            float pv[4];
            float rs = 0.f;
#pragma unroll
            for (int nb = 0; nb < 4; nb++) {
                pv[nb] = __expf(s_[nb][r] - mn);
                rs += pv[nb];
            }
#pragma unroll
            for (int off = 1; off <= 8; off <<= 1)
                rs += __shfl_xor(rs, off, 64);
            l_[r] = l_[r] * es + rs;
#pragma unroll
            for (int nb = 0; nb < 4; nb++) o_[nb][r] *= es;
            int qrl = g * 4 + r;
            int swz = (qrl & 7) << 4;
#pragma unroll
            for (int nb = 0; nb < 4; nb++) {
                int byte = (qrl * 128 + (nb * 16 + c) * 2) ^ swz;
                *reinterpret_cast<unsigned short*>((char*)pbuf + byte) = f2bf(pv[nb]);
            }
        }
        short8v aP[2];
#pragma unroll
        for (int kb = 0; kb < 2; kb++) {
            int byte = (c * 128 + kb * 64 + g * 16) ^ ((c & 7) << 4);
            aP[kb] = *reinterpret_cast<short8v*>((char*)pbuf + byte);
        }
#pragma unroll
        for (int nb = 0; nb < 4; nb++) {
            int dh = nb * 16 + c;
#pragma unroll
            for (int kb = 0; kb < 2; kb++) {
                int byte = (dh * 128 + kb * 64 + g * 16) ^ ((dh & 7) << 4);
                short8v bv = *reinterpret_cast<short8v*>((char*)vt_lds + byte);
                o_[nb] = __builtin_amdgcn_mfma_f32_16x16x32_bf16(aP[kb], bv, o_[nb], 0, 0, 0);
            }
        }
    }

    float inv_[4];
#pragma unroll
    for (int r = 0; r < 4; r++) inv_[r] = 1.f / l_[r];
#pragma unroll
    for (int nb = 0; nb < 4; nb++) {
        int col = h * DH + nb * 16 + c;
#pragma unroll
        for (int r = 0; r < 4; r++) {
            int row = q0 + wid * 16 + g * 4 + r;
            O[((size_t)b * Nn + row) * Cc + col] = f2bf(o_[nb][r] * inv_[r]);
        }
    }
}

// ---------------------------------------------------------------------------
// kernel_launch
// ---------------------------------------------------------------------------
extern "C" void kernel_launch(void* const* d_in, const int* in_sizes, int n_in,
                              void* d_out, int out_size, void* d_ws, size_t ws_size,
                              hipStream_t stream) {
    const float* x        = (const float*)d_in[0];
    const int*   pos_ids  = (const int*)d_in[1];
    const int*   tpos_ids = (const int*)d_in[2];
    const float* qkv_w    = (const float*)d_in[3];
    const float* qkv_b    = (const float*)d_in[4];
    const float* proj_w   = (const float*)d_in[5];
    const float* proj_b   = (const float*)d_in[6];
    const float* qn_w     = (const float*)d_in[7];
    const float* kn_w     = (const float*)d_in[8];
    const float* ln1_w    = (const float*)d_in[9];
    const float* ln2_w    = (const float*)d_in[10];
    const float* gate_w   = (const float*)d_in[11];
    const float* up_w     = (const float*)d_in[12];
    const float* down_w   = (const float*)d_in[13];
    float* out = (float*)d_out;
    char*  wsb = (char*)d_ws;

    // workspace regions (bytes)
    unsigned short* Wp   = (unsigned short*)(wsb);              // 25.2 MB packed weights
    unsigned short* P1   = (unsigned short*)(wsb + 25165824);   // qkv / proj-partials / t
    unsigned short* P2   = (unsigned short*)(wsb + 46137344);   // QKV bf16 / u / down partials
    unsigned short* P3   = (unsigned short*)(wsb + 67108864);   // xn/o/y bf16 (5.24 MB)
    float*          hb   = (float*)(wsb + 72351744);            // 10.49 MB fp32
    unsigned short* Qbf  = P2;
    unsigned short* Kbf  = P2 + 2621440;
    unsigned short* Vbf  = P2 + 5242880;

    // 1. xn = RMS(x, ln1) -> bf16
    rms_bf16<<<Mrows, 256, 0, stream>>>(x, ln1_w, P3);
    // 2. pack qkv weights; qkv GEMM -> bf16 (480 blocks)
    pack_w<<<4608, 256, 0, stream>>>(qkv_w, Wp, Cc, 3 * Cc);
    gemm128<1, true, false, 1><<<dim3(Mrows / 128, 24), 256, 0, stream>>>(
        P3, Wp, qkv_b, nullptr, nullptr, P1, Cc, 3 * Cc);
    // 3. split + q/k RMS + RoPE (bf16)
    split_rope<<<Mrows, 256, 0, stream>>>(P1, qn_w, kn_w, pos_ids, tpos_ids,
                                          Qbf, Kbf, Vbf);
    // 4. attention -> obf (bf16, (B,N,C))
    attn_mfma<<<dim3(Nn / 64, Bb * Hh), 256, 0, stream>>>(Qbf, Kbf, Vbf, P3);
    // 5. proj split-K=2 -> fp32 partials in P1; combine: hb = x + bias + p0 + p1
    pack_w<<<1536, 256, 0, stream>>>(proj_w, Wp, Cc, Cc);
    gemm128<0, false, false, 2><<<dim3(Mrows / 128, 8, 2), 256, 0, stream>>>(
        P3, Wp, nullptr, nullptr, nullptr, (float*)P1, Cc, Cc);
    combine_proj<<<Mrows * Cc / 1024, 256, 0, stream>>>(x, proj_b, (float*)P1, hb);
    // 6. y = RMS(h, ln2) -> bf16
    rms_bf16<<<Mrows, 256, 0, stream>>>(hb, ln2_w, P3);
    // 7. u = y @ up_w -> bf16 (P2)   (640 blocks)
    pack_w<<<6144, 256, 0, stream>>>(up_w, Wp, Cc, Ii);
    gemm128<1, false, false, 1><<<dim3(Mrows / 128, 32), 256, 0, stream>>>(
        P3, Wp, nullptr, nullptr, nullptr, P2, Cc, Ii);
    // 8. t = silu(y @ gate_w) * u -> bf16 (P1)
    pack_w<<<6144, 256, 0, stream>>>(gate_w, Wp, Cc, Ii);
    gemm128<2, false, false, 1><<<dim3(Mrows / 128, 32), 256, 0, stream>>>(
        P3, Wp, nullptr, nullptr, P2, P1, Cc, Ii);
    // 9. down split-K=4 -> bf16 partials in P2; out = hb + sum(p_z)
    pack_w<<<6144, 256, 0, stream>>>(down_w, Wp, Ii, Cc);
    gemm128<1, false, false, 4><<<dim3(Mrows / 128, 8, 4), 256, 0, stream>>>(
        P1, Wp, nullptr, nullptr, nullptr, P2, Ii, Cc);
    combine_down4<<<Mrows * Cc / 1024, 256, 0, stream>>>(hb, P2, out);
}

// Round 9
// 287.119 us; speedup vs baseline: 1.1044x; 1.0167x over previous
//
#include <hip/hip_runtime.h>
#include <math.h>

// Problem constants (fixed by setup_inputs)
constexpr int Bb  = 2;
constexpr int Nn  = 1280;
constexpr int Cc  = 1024;
constexpr int Hh  = 16;
constexpr int DH  = 64;
constexpr int Ii  = 4096;
constexpr int Tt  = 256;    // text_len
constexpr int BSz = 128;    // block_size
constexpr int L1  = 4;      // len1
constexpr int Mrows = Bb * Nn;  // 2560

typedef __attribute__((ext_vector_type(8))) short short8v;
typedef __attribute__((ext_vector_type(4))) float f32x4;

__device__ __forceinline__ int segof(int n) {
    return n < Tt ? 0 : (n < Tt + L1 * BSz ? 1 : 2);
}
__device__ __forceinline__ unsigned short f2bf(float f) {
    unsigned int u = __float_as_uint(f);
    u += 0x7fffu + ((u >> 16) & 1u);        // RNE
    return (unsigned short)(u >> 16);
}
__device__ __forceinline__ float bf2f(unsigned short h) {
    return __uint_as_float(((unsigned int)h) << 16);
}

// bijective XCD swizzle for nwg % 8 == 0
__device__ __forceinline__ int xcd_swz(int lin, int nwg) {
    int cpx = nwg >> 3;
    return (lin & 7) * cpx + (lin >> 3);
}

// ---------------------------------------------------------------------------
// RMSNorm fp32 -> bf16 out: one block per row, 256 threads, C=1024
// ---------------------------------------------------------------------------
__global__ __launch_bounds__(256)
void rms_bf16(const float* __restrict__ in, const float* __restrict__ w,
              unsigned short* __restrict__ out) {
    int row = blockIdx.x;
    int n   = row % Nn;
    int seg = segof(n);
    const float* x = in + (size_t)row * Cc;
    int t = threadIdx.x;
    float4 xv = reinterpret_cast<const float4*>(x)[t];
    float ss = xv.x * xv.x + xv.y * xv.y + xv.z * xv.z + xv.w * xv.w;
#pragma unroll
    for (int off = 32; off; off >>= 1) ss += __shfl_down(ss, off, 64);
    __shared__ float red[4];
    __shared__ float s_r;
    int lane = t & 63, wid = t >> 6;
    if (lane == 0) red[wid] = ss;
    __syncthreads();
    if (t == 0) s_r = rsqrtf((red[0] + red[1] + red[2] + red[3]) * (1.0f / Cc) + 1e-6f);
    __syncthreads();
    float r = s_r;
    float4 wv = reinterpret_cast<const float4*>(w + (size_t)seg * Cc)[t];
    ushort4 ov;
    ov.x = f2bf(wv.x * xv.x * r);
    ov.y = f2bf(wv.y * xv.y * r);
    ov.z = f2bf(wv.z * xv.z * r);
    ov.w = f2bf(wv.w * xv.w * r);
    *reinterpret_cast<ushort4*>(&out[(size_t)row * Cc + t * 4]) = ov;
}

// ---------------------------------------------------------------------------
// Pack fp32 weights [3][K][Nd] into fragment-linear bf16 layout:
// chunk (kt32, cb, fr, lane) holds 8 bf16: element j =
//   W[seg][kt32*32 + (lane>>4)*8 + j][cb*128 + fr*16 + (lane&15)]
// ---------------------------------------------------------------------------
__global__ __launch_bounds__(256)
void pack_w(const float* __restrict__ W, unsigned short* __restrict__ PB,
            int K, int Nd) {
    size_t idx = (size_t)blockIdx.x * 256 + threadIdx.x;   // chunk id
    size_t cpseg = (size_t)K * Nd / 8;
    int s = (int)(idx / cpseg);
    size_t rm = idx % cpseg;
    int lane = (int)(rm & 63);
    int fr   = (int)((rm >> 6) & 7);
    size_t tile = rm >> 9;                  // kt32*(Nd/128)+cb
    int nct = Nd >> 7;
    int cb = (int)(tile % nct);
    int kt = (int)(tile / nct);
    int col = cb * 128 + fr * 16 + (lane & 15);
    int k0  = kt * 32 + (lane >> 4) * 8;
    const float* src = W + ((size_t)s * K + k0) * Nd + col;
    unsigned short o[8];
#pragma unroll
    for (int j = 0; j < 8; j++) o[j] = f2bf(src[(size_t)j * Nd]);
    short8v v;
#pragma unroll
    for (int j = 0; j < 8; j++) v[j] = (short)o[j];
    *reinterpret_cast<short8v*>(&PB[idx * 8]) = v;
}

// ---------------------------------------------------------------------------
// bf16 MFMA GEMM (round-6 proven structure + XCD swizzle): 64x128 tile,
// BK=64, 4 waves (2x2, wave = 32x64), reg-staged prefetch (loads for kt+1
// issued under MFMA of kt, held in VGPRs across the barrier).
// OUTMODE: 0 = f32 out, 1 = bf16 out.  NZ: split-K; partial z at z*Mrows*Nd.
// ---------------------------------------------------------------------------
template <int OUTMODE, bool BIAS, int NZ>
__global__ __launch_bounds__(256)
void gemm64(const unsigned short* __restrict__ A,
            const unsigned short* __restrict__ PB,
            const float* __restrict__ bias, void* __restrict__ outp,
            int K, int Nd) {
    __shared__ __align__(16) unsigned short lds[12288];  // A 8KB | B 16KB
    int bx = blockIdx.x, by = blockIdx.y, bz = (NZ > 1) ? blockIdx.z : 0;
    {
        int gx = gridDim.x, gy = gridDim.y, gz = (NZ > 1) ? gridDim.z : 1;
        int lin = bx + gx * (by + gy * bz);
        int swz = xcd_swz(lin, gx * gy * gz);
        bx = swz % gx; swz /= gx;
        by = swz % gy; bz = swz / gy;
    }
    int rb = bx * 64, cb = by;
    int seg = segof(rb % Nn);
    int tid = threadIdx.x, lane = tid & 63, wid = tid >> 6;
    int wr = wid >> 1, wc = wid & 1;
    int g = lane >> 4, c_ = lane & 15;
    const unsigned short* PBseg = PB + (size_t)seg * K * Nd;
    const int nct = Nd >> 7;
    const int Keff = K / NZ;
    const int nKt = Keff >> 6;
    const int kz = bz * Keff;

    f32x4 acc[2][4];
#pragma unroll
    for (int m = 0; m < 2; m++)
#pragma unroll
        for (int n = 0; n < 4; n++) acc[m][n] = (f32x4){0.f, 0.f, 0.f, 0.f};

    short8v av[2], bv[4];
    auto load_tile = [&](int kt) {
#pragma unroll
        for (int i = 0; i < 2; i++) {
            int c = tid + i * 256;              // 0..511
            int rf = c >> 7, kb = (c >> 6) & 1, lc = c & 63;
            int row = rb + rf * 16 + (lc & 15);
            int k0  = kz + kt * 64 + kb * 32 + (lc >> 4) * 8;
            av[i] = *reinterpret_cast<const short8v*>(&A[(size_t)row * K + k0]);
        }
#pragma unroll
        for (int i = 0; i < 4; i++) {
            int c = tid + i * 256;              // 0..1023
            int cf = c >> 7, kb = (c >> 6) & 1, lc = c & 63;
            int kt32 = (kz >> 5) + kt * 2 + kb;
            bv[i] = *reinterpret_cast<const short8v*>(
                &PBseg[((((size_t)kt32 * nct + cb) * 8 + cf) * 64 + lc) * 8]);
        }
    };

    load_tile(0);
    for (int kt = 0; kt < nKt; ++kt) {
        __syncthreads();                        // prev iter's ds_reads done
#pragma unroll
        for (int i = 0; i < 2; i++)
            *reinterpret_cast<short8v*>(&lds[(size_t)(tid + i * 256) * 8]) = av[i];
#pragma unroll
        for (int i = 0; i < 4; i++)
            *reinterpret_cast<short8v*>(&lds[4096 + (size_t)(tid + i * 256) * 8]) = bv[i];
        __syncthreads();
        if (kt + 1 < nKt) load_tile(kt + 1);    // in flight under MFMA
        short8v afr[2][2], bfr[4][2];
#pragma unroll
        for (int m = 0; m < 2; m++)
#pragma unroll
            for (int kb = 0; kb < 2; kb++)
                afr[m][kb] = *reinterpret_cast<short8v*>(
                    &lds[(((wr * 2 + m) * 2 + kb) * 64 + lane) * 8]);
#pragma unroll
        for (int n = 0; n < 4; n++)
#pragma unroll
            for (int kb = 0; kb < 2; kb++)
                bfr[n][kb] = *reinterpret_cast<short8v*>(
                    &lds[4096 + (((wc * 4 + n) * 2 + kb) * 64 + lane) * 8]);
#pragma unroll
        for (int m = 0; m < 2; m++)
#pragma unroll
            for (int n = 0; n < 4; n++)
#pragma unroll
                for (int kb = 0; kb < 2; kb++)
                    acc[m][n] = __builtin_amdgcn_mfma_f32_16x16x32_bf16(
                        afr[m][kb], bfr[n][kb], acc[m][n], 0, 0, 0);
    }

    // epilogue: C/D layout col=lane&15, row=(lane>>4)*4+r
    float* outf = (float*)outp;
    unsigned short* outh = (unsigned short*)outp;
    size_t zoff = (NZ > 1) ? (size_t)bz * Mrows * Nd : 0;
#pragma unroll
    for (int n = 0; n < 4; n++) {
        int col = cb * 128 + wc * 64 + n * 16 + c_;
        float bvv = BIAS ? bias[(size_t)seg * Nd + col] : 0.f;
#pragma unroll
        for (int m = 0; m < 2; m++) {
#pragma unroll
            for (int r = 0; r < 4; r++) {
                int row = rb + wr * 32 + m * 16 + g * 4 + r;
                float v = acc[m][n][r] + bvv;
                if (OUTMODE == 0) outf[zoff + (size_t)row * Nd + col] = v;
                else              outh[zoff + (size_t)row * Nd + col] = f2bf(v);
            }
        }
    }
}

// ---------------------------------------------------------------------------
// Fused gate+up GEMM: t = silu(y@gate) * (y@up), 64x128 tile, BK=32,
// reg-staged prefetch, 16 MFMA : 10 ds_read per step. K=Cc, Nd=Ii.
// ---------------------------------------------------------------------------
__global__ __launch_bounds__(256)
void gemm_gu(const unsigned short* __restrict__ A,
             const unsigned short* __restrict__ PG,
             const unsigned short* __restrict__ PU,
             unsigned short* __restrict__ outp) {
    __shared__ __align__(16) unsigned short lds[10240];  // A 4KB | G 8KB | U 8KB
    int bx = blockIdx.x, by = blockIdx.y;
    {
        int lin = bx + gridDim.x * by;
        int swz = xcd_swz(lin, gridDim.x * gridDim.y);
        bx = swz % gridDim.x; by = swz / gridDim.x;
    }
    int rb = bx * 64, cb = by;
    int seg = segof(rb % Nn);
    int tid = threadIdx.x, lane = tid & 63, wid = tid >> 6;
    int wr = wid >> 1, wc = wid & 1;
    int g = lane >> 4, c_ = lane & 15;
    const int nct = Ii >> 7;                    // 32
    const unsigned short* PGseg = PG + (size_t)seg * Cc * Ii;
    const unsigned short* PUseg = PU + (size_t)seg * Cc * Ii;

    f32x4 accG[2][4], accU[2][4];
#pragma unroll
    for (int m = 0; m < 2; m++)
#pragma unroll
        for (int n = 0; n < 4; n++) {
            accG[m][n] = (f32x4){0.f, 0.f, 0.f, 0.f};
            accU[m][n] = (f32x4){0.f, 0.f, 0.f, 0.f};
        }

    // staging: A 1 chunk, G 2, U 2
    int mf0 = tid >> 6, lc0 = tid & 63;
    const unsigned short* gA =
        &A[(size_t)(rb + mf0 * 16 + (lc0 & 15)) * Cc + (lc0 >> 4) * 8];
    const size_t bstep = (size_t)nct * 4096;    // shorts per kt32
    short8v av, gv[2], uv[2];
    auto load_tile = [&](int kt) {
        av = *reinterpret_cast<const short8v*>(gA + kt * 32);
#pragma unroll
        for (int i = 0; i < 2; i++) {
            int c = tid + i * 256;              // 0..511
            int cf = c >> 6, lc = c & 63;
            size_t off = (((size_t)kt * nct + cb) * 8 + cf) * 64 * 8 + (size_t)lc * 8;
            gv[i] = *reinterpret_cast<const short8v*>(PGseg + off);
            uv[i] = *reinterpret_cast<const short8v*>(PUseg + off);
        }
    };

    const int nKt = Cc >> 5;                    // 32
    load_tile(0);
    for (int kt = 0; kt < nKt; ++kt) {
        __syncthreads();
        *reinterpret_cast<short8v*>(&lds[(size_t)tid * 8]) = av;
#pragma unroll
        for (int i = 0; i < 2; i++) {
            *reinterpret_cast<short8v*>(&lds[2048 + (size_t)(tid + i * 256) * 8]) = gv[i];
            *reinterpret_cast<short8v*>(&lds[6144 + (size_t)(tid + i * 256) * 8]) = uv[i];
        }
        __syncthreads();
        if (kt + 1 < nKt) load_tile(kt + 1);
        short8v afr[2], gfr[4], ufr[4];
#pragma unroll
        for (int m = 0; m < 2; m++)
            afr[m] = *reinterpret_cast<short8v*>(&lds[((wr * 2 + m) * 64 + lane) * 8]);
#pragma unroll
        for (int n = 0; n < 4; n++) {
            gfr[n] = *reinterpret_cast<short8v*>(&lds[2048 + ((wc * 4 + n) * 64 + lane) * 8]);
            ufr[n] = *reinterpret_cast<short8v*>(&lds[6144 + ((wc * 4 + n) * 64 + lane) * 8]);
        }
#pragma unroll
        for (int m = 0; m < 2; m++)
#pragma unroll
            for (int n = 0; n < 4; n++) {
                accG[m][n] = __builtin_amdgcn_mfma_f32_16x16x32_bf16(
                    afr[m], gfr[n], accG[m][n], 0, 0, 0);
                accU[m][n] = __builtin_amdgcn_mfma_f32_16x16x32_bf16(
                    afr[m], ufr[n], accU[m][n], 0, 0, 0);
            }
    }

    // epilogue: t = silu(g) * u
#pragma unroll
    for (int n = 0; n < 4; n++) {
        int col = cb * 128 + wc * 64 + n * 16 + c_;
#pragma unroll
        for (int m = 0; m < 2; m++) {
#pragma unroll
            for (int r = 0; r < 4; r++) {
                int row = rb + wr * 32 + m * 16 + g * 4 + r;
                float gval = accG[m][n][r], uval = accU[m][n][r];
                float t = gval / (1.f + __expf(-gval)) * uval;
                outp[(size_t)row * Ii + col] = f2bf(t);
            }
        }
    }
}

// ---------------------------------------------------------------------------
// proj combine: h(out) = x + bias[seg] + p0 + p1   (fp32 partials)
// ---------------------------------------------------------------------------
__global__ __launch_bounds__(256)
void combine_proj(const float* __restrict__ x, const float* __restrict__ bias,
                  const float* __restrict__ p, float* __restrict__ hb) {
    int i = blockIdx.x * 256 + threadIdx.x;     // float4 index
    int base = i * 4;
    int col = base % Cc;
    int n   = (base / Cc) % Nn;
    int seg = segof(n);
    float4 a = reinterpret_cast<const float4*>(x)[i];
    float4 b = *reinterpret_cast<const float4*>(&bias[(size_t)seg * Cc + col]);
    float4 p0 = reinterpret_cast<const float4*>(p)[i];
    float4 p1 = reinterpret_cast<const float4*>(p)[i + Mrows * Cc / 4];
    float4 r;
    r.x = a.x + b.x + p0.x + p1.x;
    r.y = a.y + b.y + p0.y + p1.y;
    r.z = a.z + b.z + p0.z + p1.z;
    r.w = a.w + b.w + p0.w + p1.w;
    reinterpret_cast<float4*>(hb)[i] = r;
}

// ---------------------------------------------------------------------------
// down combine: out = h(out) + sum_z bf2f(p_z)    (bf16 partials, NZ=4)
// ---------------------------------------------------------------------------
__global__ __launch_bounds__(256)
void combine_down4(const unsigned short* __restrict__ p,
                   float* __restrict__ out) {
    int i = blockIdx.x * 256 + threadIdx.x;     // 4-elem group
    float4 a = reinterpret_cast<const float4*>(out)[i];
#pragma unroll
    for (int z = 0; z < 4; z++) {
        ushort4 u = *reinterpret_cast<const ushort4*>(&p[(size_t)z * Mrows * Cc + i * 4]);
        a.x += bf2f(u.x); a.y += bf2f(u.y); a.z += bf2f(u.z); a.w += bf2f(u.w);
    }
    reinterpret_cast<float4*>(out)[i] = a;
}

// ---------------------------------------------------------------------------
// Split qkv(bf16) + per-head q/k RMSNorm + RoPE -> bf16 Q,K,V (bh, n, dh)
// ---------------------------------------------------------------------------
__global__ __launch_bounds__(256)
void split_rope(const unsigned short* __restrict__ qkv,
                const float* __restrict__ qn_w, const float* __restrict__ kn_w,
                const int* __restrict__ pos_ids, const int* __restrict__ tpos_ids,
                unsigned short* __restrict__ Q, unsigned short* __restrict__ K,
                unsigned short* __restrict__ V) {
    int row = blockIdx.x;   // b*N + n
    int b = row / Nn, n = row % Nn;
    int seg = segof(n);
    int lane = threadIdx.x & 63, wid = threadIdx.x >> 6;
    int pos = (n < Tt) ? tpos_ids[n] : pos_ids[n - Tt];
    int j = lane & 31;
    float ang = (float)pos * exp2f(-(float)j * (13.287712379549449f / 32.f));
    float cv = cosf(ang), sv = sinf(ang);
    float qw = qn_w[seg * DH + lane], kw = kn_w[seg * DH + lane];
    for (int h = wid; h < Hh; h += 4) {
        const unsigned short* base = qkv + (size_t)row * (3 * Cc) + h * DH + lane;
        float q = bf2f(base[0]), k = bf2f(base[Cc]), v = bf2f(base[2 * Cc]);
        float qs = q * q, ks = k * k;
#pragma unroll
        for (int off = 32; off; off >>= 1) {
            qs += __shfl_xor(qs, off, 64);
            ks += __shfl_xor(ks, off, 64);
        }
        q = q * rsqrtf(qs * (1.f / DH) + 1e-6f) * qw;
        k = k * rsqrtf(ks * (1.f / DH) + 1e-6f) * kw;
        float qp = __shfl_xor(q, 32, 64);
        float kp = __shfl_xor(k, 32, 64);
        float qo = q * cv + ((lane < 32) ? -qp * sv : qp * sv);
        float ko = k * cv + ((lane < 32) ? -kp * sv : kp * sv);
        size_t oidx = ((size_t)(b * Hh + h) * Nn + n) * DH + lane;
        Q[oidx] = f2bf(qo);
        K[oidx] = f2bf(ko);
        V[oidx] = f2bf(v);
    }
}

// ---------------------------------------------------------------------------
// MFMA flash attention (unchanged — verified)
// ---------------------------------------------------------------------------
__global__ __launch_bounds__(256)
void attn_mfma(const unsigned short* __restrict__ Qg,
               const unsigned short* __restrict__ Kg,
               const unsigned short* __restrict__ Vg,
               unsigned short* __restrict__ O) {
    __shared__ __align__(16) unsigned short k_lds[64 * 64];   // 8 KB
    __shared__ __align__(16) unsigned short vt_lds[64 * 64];  // 8 KB
    __shared__ __align__(16) unsigned short p_lds[4][16 * 64];// 8 KB

    int qt = blockIdx.x;
    int bh = blockIdx.y;
    int b = bh >> 4, h = bh & 15;
    int tid = threadIdx.x, lane = tid & 63, wid = tid >> 6;
    int g = lane >> 4, c = lane & 15;

    const size_t headoff = (size_t)bh * Nn * DH;
    int q0 = qt * 64;
    bool qtext = q0 < Tt;
    int qb = qtext ? 0 : (q0 - Tt) / BSz;

    int qrow_frag = q0 + wid * 16 + c;
    short8v aq[2];
#pragma unroll
    for (int kb = 0; kb < 2; kb++)
        aq[kb] = *reinterpret_cast<const short8v*>(
            &Qg[headoff + (size_t)qrow_frag * DH + kb * 32 + g * 8]);

    unsigned short* pbuf = &p_lds[wid][0];

    f32x4 o_[4];
#pragma unroll
    for (int nb = 0; nb < 4; nb++) o_[nb] = (f32x4){0.f, 0.f, 0.f, 0.f};
    float m_[4] = {-3.4e38f, -3.4e38f, -3.4e38f, -3.4e38f};
    float l_[4] = {0.f, 0.f, 0.f, 0.f};

    int tr = tid >> 2, tc = tid & 3;

    for (int kt = 0; kt < Nn / 64; kt++) {
        int kbase = kt * 64;
        bool vis, diag = false;
        if (qtext) {
            vis = (kbase <= q0);
            diag = (kbase == q0);
        } else if (kbase < Tt) {
            vis = true;
        } else {
            int kb = (kbase - Tt) / BSz;
            vis = (qb < L1) ? (kb <= qb)
                            : ((kb < L1 && qb - L1 > kb) || kb == qb);
        }
        if (!vis) continue;

        __syncthreads();
        {
            const unsigned short* ks = &Kg[headoff + (size_t)(kbase + tr) * DH];
            const unsigned short* vs = &Vg[headoff + (size_t)(kbase + tr) * DH];
#pragma unroll
            for (int i = 0; i < 2; i++) {
                int ch = tc + i * 4;
                short8v kv = *reinterpret_cast<const short8v*>(ks + ch * 8);
                int byte = (tr * 128 + ch * 16) ^ ((tr & 7) << 4);
                *reinterpret_cast<short8v*>((char*)k_lds + byte) = kv;
                short8v vv = *reinterpret_cast<const short8v*>(vs + ch * 8);
#pragma unroll
                for (int j = 0; j < 8; j++) {
                    int dh = ch * 8 + j;
                    int vbyte = (dh * 128 + tr * 2) ^ ((dh & 7) << 4);
                    *reinterpret_cast<unsigned short*>((char*)vt_lds + vbyte) =
                        (unsigned short)vv[j];
                }
            }
        }
        __syncthreads();

        f32x4 s_[4];
#pragma unroll
        for (int nb = 0; nb < 4; nb++) s_[nb] = (f32x4){0.f, 0.f, 0.f, 0.f};
#pragma unroll
        for (int nb = 0; nb < 4; nb++) {
            int kil = nb * 16 + c;
#pragma unroll
            for (int kb = 0; kb < 2; kb++) {
                int byte = (kil * 128 + kb * 64 + g * 16) ^ ((kil & 7) << 4);
                short8v bk = *reinterpret_cast<short8v*>((char*)k_lds + byte);
                s_[nb] = __builtin_amdgcn_mfma_f32_16x16x32_bf16(aq[kb], bk, s_[nb], 0, 0, 0);
            }
        }
#pragma unroll
        for (int nb = 0; nb < 4; nb++) {
#pragma unroll
            for (int r = 0; r < 4; r++) {
                float sv = s_[nb][r] * 0.125f;
                if (diag) {
                    int qrl = wid * 16 + g * 4 + r;
                    int kcl = nb * 16 + c;
                    if (qrl < kcl) sv = -3.4e38f;
                }
                s_[nb][r] = sv;
            }
        }
#pragma unroll
        for (int r = 0; r < 4; r++) {
            float mx = fmaxf(fmaxf(s_[0][r], s_[1][r]), fmaxf(s_[2][r], s_[3][r]));
#pragma unroll
            for (int off = 1; off <= 8; off <<= 1)
                mx = fmaxf(mx, __shfl_xor(mx, off, 64));
            float mn = fmaxf(m_[r], mx);
            float es = __expf(m_[r] - mn);
            m_[r] = mn;
            float pv[4];
            float rs = 0.f;
#pragma unroll
            for (int nb = 0; nb < 4; nb++) {
                pv[nb] = __expf(s_[nb][r] - mn);
                rs += pv[nb];
            }
#pragma unroll
            for (int off = 1; off <= 8; off <<= 1)
                rs += __shfl_xor(rs, off, 64);
            l_[r] = l_[r] * es + rs;
#pragma unroll
            for (int nb = 0; nb < 4; nb++) o_[nb][r] *= es;
            int qrl = g * 4 + r;
            int swz = (qrl & 7) << 4;
#pragma unroll
            for (int nb = 0; nb < 4; nb++) {
                int byte = (qrl * 128 + (nb * 16 + c) * 2) ^ swz;
                *reinterpret_cast<unsigned short*>((char*)pbuf + byte) = f2bf(pv[nb]);
            }
        }
        short8v aP[2];
#pragma unroll
        for (int kb = 0; kb < 2; kb++) {
            int byte = (c * 128 + kb * 64 + g * 16) ^ ((c & 7) << 4);
            aP[kb] = *reinterpret_cast<short8v*>((char*)pbuf + byte);
        }
#pragma unroll
        for (int nb = 0; nb < 4; nb++) {
            int dh = nb * 16 + c;
#pragma unroll
            for (int kb = 0; kb < 2; kb++) {
                int byte = (dh * 128 + kb * 64 + g * 16) ^ ((dh & 7) << 4);
                short8v bv = *reinterpret_cast<short8v*>((char*)vt_lds + byte);
                o_[nb] = __builtin_amdgcn_mfma_f32_16x16x32_bf16(aP[kb], bv, o_[nb], 0, 0, 0);
            }
        }
    }

    float inv_[4];
#pragma unroll
    for (int r = 0; r < 4; r++) inv_[r] = 1.f / l_[r];
#pragma unroll
    for (int nb = 0; nb < 4; nb++) {
        int col = h * DH + nb * 16 + c;
#pragma unroll
        for (int r = 0; r < 4; r++) {
            int row = q0 + wid * 16 + g * 4 + r;
            O[((size_t)b * Nn + row) * Cc + col] = f2bf(o_[nb][r] * inv_[r]);
        }
    }
}

// ---------------------------------------------------------------------------
// kernel_launch
// ---------------------------------------------------------------------------
extern "C" void kernel_launch(void* const* d_in, const int* in_sizes, int n_in,
                              void* d_out, int out_size, void* d_ws, size_t ws_size,
                              hipStream_t stream) {
    const float* x        = (const float*)d_in[0];
    const int*   pos_ids  = (const int*)d_in[1];
    const int*   tpos_ids = (const int*)d_in[2];
    const float* qkv_w    = (const float*)d_in[3];
    const float* qkv_b    = (const float*)d_in[4];
    const float* proj_w   = (const float*)d_in[5];
    const float* proj_b   = (const float*)d_in[6];
    const float* qn_w     = (const float*)d_in[7];
    const float* kn_w     = (const float*)d_in[8];
    const float* ln1_w    = (const float*)d_in[9];
    const float* ln2_w    = (const float*)d_in[10];
    const float* gate_w   = (const float*)d_in[11];
    const float* up_w     = (const float*)d_in[12];
    const float* down_w   = (const float*)d_in[13];
    float* out = (float*)d_out;                 // also used as h buffer
    char*  wsb = (char*)d_ws;

    // workspace regions (bytes), peak 76.5 MB
    unsigned short* WA  = (unsigned short*)(wsb);               // 25.2 MB (qkv_p/proj_p/gate_p/down_p)
    unsigned short* WB  = (unsigned short*)(wsb + 25165824);    // 25.2 MB (qkvb / up_p / down partials)
    unsigned short* Tb  = (unsigned short*)(wsb + 50331648);    // 21.0 MB (QKV / proj partials / t)
    unsigned short* P3  = (unsigned short*)(wsb + 71303168);    //  5.2 MB (xn / obf / y)
    unsigned short* Qbf = Tb;
    unsigned short* Kbf = Tb + 2621440;
    unsigned short* Vbf = Tb + 5242880;

    // 1. xn = RMS(x, ln1) -> bf16 (P3)
    rms_bf16<<<Mrows, 256, 0, stream>>>(x, ln1_w, P3);
    // 2. pack qkv -> WA; qkv GEMM -> qkvb (WB)
    pack_w<<<4608, 256, 0, stream>>>(qkv_w, WA, Cc, 3 * Cc);
    gemm64<1, true, 1><<<dim3(Mrows / 64, 24), 256, 0, stream>>>(
        P3, WA, qkv_b, WB, Cc, 3 * Cc);
    // 3. split + q/k RMS + RoPE -> Q,K,V (Tb)
    split_rope<<<Mrows, 256, 0, stream>>>(WB, qn_w, kn_w, pos_ids, tpos_ids,
                                          Qbf, Kbf, Vbf);
    // 4. attention -> obf (P3)
    attn_mfma<<<dim3(Nn / 64, Bb * Hh), 256, 0, stream>>>(Qbf, Kbf, Vbf, P3);
    // 5. proj split-K=2 -> fp32 partials (Tb); combine -> h in out
    pack_w<<<1536, 256, 0, stream>>>(proj_w, WA, Cc, Cc);
    gemm64<0, false, 2><<<dim3(Mrows / 64, 8, 2), 256, 0, stream>>>(
        P3, WA, nullptr, (float*)Tb, Cc, Cc);
    combine_proj<<<Mrows * Cc / 1024, 256, 0, stream>>>(x, proj_b, (float*)Tb, out);
    // 6. y = RMS(h, ln2) -> bf16 (P3)
    rms_bf16<<<Mrows, 256, 0, stream>>>(out, ln2_w, P3);
    // 7. fused: t = silu(y@gate) * (y@up) -> Tb
    pack_w<<<6144, 256, 0, stream>>>(gate_w, WA, Cc, Ii);
    pack_w<<<6144, 256, 0, stream>>>(up_w, WB, Cc, Ii);
    gemm_gu<<<dim3(Mrows / 64, 32), 256, 0, stream>>>(P3, WA, WB, Tb);
    // 8. down split-K=4 -> bf16 partials (WB); out = h + sum(p_z)
    pack_w<<<6144, 256, 0, stream>>>(down_w, WA, Ii, Cc);
    gemm64<1, false, 4><<<dim3(Mrows / 64, 8, 4), 256, 0, stream>>>(
        Tb, WA, nullptr, WB, Ii, Cc);
    combine_down4<<<Mrows * Cc / 1024, 256, 0, stream>>>(WB, out);
}

// Round 10
// 275.216 us; speedup vs baseline: 1.1522x; 1.0432x over previous
//
#include <hip/hip_runtime.h>
#include <math.h>

// Problem constants (fixed by setup_inputs)
constexpr int Bb  = 2;
constexpr int Nn  = 1280;
constexpr int Cc  = 1024;
constexpr int Hh  = 16;
constexpr int DH  = 64;
constexpr int Ii  = 4096;
constexpr int Tt  = 256;    // text_len
constexpr int BSz = 128;    // block_size
constexpr int L1  = 4;      // len1
constexpr int Mrows = Bb * Nn;  // 2560

typedef __attribute__((ext_vector_type(8))) short short8v;
typedef __attribute__((ext_vector_type(4))) float f32x4;

__device__ __forceinline__ int segof(int n) {
    return n < Tt ? 0 : (n < Tt + L1 * BSz ? 1 : 2);
}
__device__ __forceinline__ unsigned short f2bf(float f) {
    unsigned int u = __float_as_uint(f);
    u += 0x7fffu + ((u >> 16) & 1u);        // RNE
    return (unsigned short)(u >> 16);
}
__device__ __forceinline__ float bf2f(unsigned short h) {
    return __uint_as_float(((unsigned int)h) << 16);
}

// bijective XCD swizzle for nwg % 8 == 0
__device__ __forceinline__ int xcd_swz(int lin, int nwg) {
    int cpx = nwg >> 3;
    return (lin & 7) * cpx + (lin >> 3);
}

// ---------------------------------------------------------------------------
// RMSNorm fp32 -> bf16 out: one block per row, 256 threads, C=1024
// ---------------------------------------------------------------------------
__global__ __launch_bounds__(256)
void rms_bf16(const float* __restrict__ in, const float* __restrict__ w,
              unsigned short* __restrict__ out) {
    int row = blockIdx.x;
    int n   = row % Nn;
    int seg = segof(n);
    const float* x = in + (size_t)row * Cc;
    int t = threadIdx.x;
    float4 xv = reinterpret_cast<const float4*>(x)[t];
    float ss = xv.x * xv.x + xv.y * xv.y + xv.z * xv.z + xv.w * xv.w;
#pragma unroll
    for (int off = 32; off; off >>= 1) ss += __shfl_down(ss, off, 64);
    __shared__ float red[4];
    __shared__ float s_r;
    int lane = t & 63, wid = t >> 6;
    if (lane == 0) red[wid] = ss;
    __syncthreads();
    if (t == 0) s_r = rsqrtf((red[0] + red[1] + red[2] + red[3]) * (1.0f / Cc) + 1e-6f);
    __syncthreads();
    float r = s_r;
    float4 wv = reinterpret_cast<const float4*>(w + (size_t)seg * Cc)[t];
    ushort4 ov;
    ov.x = f2bf(wv.x * xv.x * r);
    ov.y = f2bf(wv.y * xv.y * r);
    ov.z = f2bf(wv.z * xv.z * r);
    ov.w = f2bf(wv.w * xv.w * r);
    *reinterpret_cast<ushort4*>(&out[(size_t)row * Cc + t * 4]) = ov;
}

// ---------------------------------------------------------------------------
// Pack fp32 weights [3][K][Nd] into fragment-linear bf16 layout:
// chunk (kt32, cb, fr, lane) holds 8 bf16: element j =
//   W[seg][kt32*32 + (lane>>4)*8 + j][cb*128 + fr*16 + (lane&15)]
// ---------------------------------------------------------------------------
__global__ __launch_bounds__(256)
void pack_w(const float* __restrict__ W, unsigned short* __restrict__ PB,
            int K, int Nd) {
    size_t idx = (size_t)blockIdx.x * 256 + threadIdx.x;   // chunk id
    size_t cpseg = (size_t)K * Nd / 8;
    int s = (int)(idx / cpseg);
    size_t rm = idx % cpseg;
    int lane = (int)(rm & 63);
    int fr   = (int)((rm >> 6) & 7);
    size_t tile = rm >> 9;                  // kt32*(Nd/128)+cb
    int nct = Nd >> 7;
    int cb = (int)(tile % nct);
    int kt = (int)(tile / nct);
    int col = cb * 128 + fr * 16 + (lane & 15);
    int k0  = kt * 32 + (lane >> 4) * 8;
    const float* src = W + ((size_t)s * K + k0) * Nd + col;
    unsigned short o[8];
#pragma unroll
    for (int j = 0; j < 8; j++) o[j] = f2bf(src[(size_t)j * Nd]);
    short8v v;
#pragma unroll
    for (int j = 0; j < 8; j++) v[j] = (short)o[j];
    *reinterpret_cast<short8v*>(&PB[idx * 8]) = v;
}

// ---------------------------------------------------------------------------
// bf16 MFMA GEMM v4: 128x128 tile, BK=32, 4 waves 2x2 (wave = 64x64, 4x4
// acc -> 8 LDS frags per 16 MFMA, the m97 ratio), reg-staged prefetch with
// pointer-bumped addresses (loads for kt+1 issued under MFMA of kt, held in
// VGPRs across the barrier — avoids the vmcnt(0) drain of gload_lds).
// OUTMODE: 0 = f32 out, 1 = bf16 out.  NZ: split-K; partial z at z*Mrows*Nd.
// ---------------------------------------------------------------------------
template <int OUTMODE, bool BIAS, int NZ>
__global__ __launch_bounds__(256, 2)
void gemm128r(const unsigned short* __restrict__ A,
              const unsigned short* __restrict__ PB,
              const float* __restrict__ bias, void* __restrict__ outp,
              int K, int Nd) {
    __shared__ __align__(16) unsigned short lds[8192];   // A 8KB | B 8KB
    int bx = blockIdx.x, by = blockIdx.y, bz = (NZ > 1) ? blockIdx.z : 0;
    {
        int gx = gridDim.x, gy = gridDim.y, gz = (NZ > 1) ? gridDim.z : 1;
        int lin = bx + gx * (by + gy * bz);
        int swz = xcd_swz(lin, gx * gy * gz);
        bx = swz % gx; swz /= gx;
        by = swz % gy; bz = swz / gy;
    }
    int rb = bx * 128, cb = by;
    int seg = segof(rb % Nn);
    int tid = threadIdx.x, lane = tid & 63, wid = tid >> 6;
    int wr = wid >> 1, wc = wid & 1;
    int g = lane >> 4, c_ = lane & 15;
    const int nct = Nd >> 7;
    const int Keff = K / NZ;
    const int nKt = Keff >> 5;
    const int kz = bz * Keff;
    const unsigned short* PBseg = PB + (size_t)seg * K * Nd;

    // pointer-bumped staging sources (chunks tid and tid+256)
    int mf0 = tid >> 6, lc0 = tid & 63;
    const unsigned short* pA0 =
        A + (size_t)(rb + mf0 * 16 + (lc0 & 15)) * K + kz + (lc0 >> 4) * 8;
    const unsigned short* pA1 = pA0 + (size_t)64 * K;
    const unsigned short* pB0 =
        PBseg + (((size_t)(kz >> 5) * nct + cb) * 8 + mf0) * 512 + (size_t)lc0 * 8;
    const unsigned short* pB1 = pB0 + 2048;
    const size_t bstep = (size_t)nct * 4096;   // shorts per K-step

    f32x4 acc[4][4];
#pragma unroll
    for (int m = 0; m < 4; m++)
#pragma unroll
        for (int n = 0; n < 4; n++) acc[m][n] = (f32x4){0.f, 0.f, 0.f, 0.f};

    short8v av[2], bv[2];
    av[0] = *reinterpret_cast<const short8v*>(pA0);
    av[1] = *reinterpret_cast<const short8v*>(pA1);
    bv[0] = *reinterpret_cast<const short8v*>(pB0);
    bv[1] = *reinterpret_cast<const short8v*>(pB1);
    pA0 += 32; pA1 += 32; pB0 += bstep; pB1 += bstep;

    for (int kt = 0; kt < nKt; ++kt) {
        __syncthreads();                        // prev iter's ds_reads done
        *reinterpret_cast<short8v*>(&lds[(size_t)tid * 8]) = av[0];
        *reinterpret_cast<short8v*>(&lds[(size_t)(tid + 256) * 8]) = av[1];
        *reinterpret_cast<short8v*>(&lds[4096 + (size_t)tid * 8]) = bv[0];
        *reinterpret_cast<short8v*>(&lds[4096 + (size_t)(tid + 256) * 8]) = bv[1];
        __syncthreads();
        if (kt + 1 < nKt) {                     // prefetch under MFMA
            av[0] = *reinterpret_cast<const short8v*>(pA0);
            av[1] = *reinterpret_cast<const short8v*>(pA1);
            bv[0] = *reinterpret_cast<const short8v*>(pB0);
            bv[1] = *reinterpret_cast<const short8v*>(pB1);
            pA0 += 32; pA1 += 32; pB0 += bstep; pB1 += bstep;
        }
        short8v afr[4], bfr[4];
#pragma unroll
        for (int m = 0; m < 4; m++)
            afr[m] = *reinterpret_cast<short8v*>(&lds[((wr * 4 + m) * 64 + lane) * 8]);
#pragma unroll
        for (int n = 0; n < 4; n++)
            bfr[n] = *reinterpret_cast<short8v*>(&lds[4096 + ((wc * 4 + n) * 64 + lane) * 8]);
#pragma unroll
        for (int m = 0; m < 4; m++)
#pragma unroll
            for (int n = 0; n < 4; n++)
                acc[m][n] = __builtin_amdgcn_mfma_f32_16x16x32_bf16(
                    afr[m], bfr[n], acc[m][n], 0, 0, 0);
    }

    // epilogue: C/D layout col=lane&15, row=(lane>>4)*4+r
    float* outf = (float*)outp;
    unsigned short* outh = (unsigned short*)outp;
    size_t zoff = (NZ > 1) ? (size_t)bz * Mrows * Nd : 0;
#pragma unroll
    for (int n = 0; n < 4; n++) {
        int col = cb * 128 + wc * 64 + n * 16 + c_;
        float bvv = BIAS ? bias[(size_t)seg * Nd + col] : 0.f;
#pragma unroll
        for (int m = 0; m < 4; m++) {
#pragma unroll
            for (int r = 0; r < 4; r++) {
                int row = rb + wr * 64 + m * 16 + g * 4 + r;
                float v = acc[m][n][r] + bvv;
                if (OUTMODE == 0) outf[zoff + (size_t)row * Nd + col] = v;
                else              outh[zoff + (size_t)row * Nd + col] = f2bf(v);
            }
        }
    }
}

// ---------------------------------------------------------------------------
// Fused gate+up GEMM v2: t = silu(y@gate)*(y@up), 128x128 tile, BK=32,
// 4 waves 2x2 (wave = 64x64, dual 4x4 acc -> 12 frags per 32 MFMA),
// pointer-bumped reg-staged prefetch. K=Cc, Nd=Ii.
// ---------------------------------------------------------------------------
__global__ __launch_bounds__(256, 2)
void gemm_gu(const unsigned short* __restrict__ A,
             const unsigned short* __restrict__ PG,
             const unsigned short* __restrict__ PU,
             unsigned short* __restrict__ outp) {
    __shared__ __align__(16) unsigned short lds[12288];  // A 8KB | G 8KB | U 8KB
    int bx = blockIdx.x, by = blockIdx.y;
    {
        int lin = bx + gridDim.x * by;
        int swz = xcd_swz(lin, gridDim.x * gridDim.y);
        bx = swz % gridDim.x; by = swz / gridDim.x;
    }
    int rb = bx * 128, cb = by;
    int seg = segof(rb % Nn);
    int tid = threadIdx.x, lane = tid & 63, wid = tid >> 6;
    int wr = wid >> 1, wc = wid & 1;
    int g = lane >> 4, c_ = lane & 15;
    const int nct = Ii >> 7;                    // 32
    const unsigned short* PGseg = PG + (size_t)seg * Cc * Ii;
    const unsigned short* PUseg = PU + (size_t)seg * Cc * Ii;

    int mf0 = tid >> 6, lc0 = tid & 63;
    const unsigned short* pA0 =
        A + (size_t)(rb + mf0 * 16 + (lc0 & 15)) * Cc + (lc0 >> 4) * 8;
    const unsigned short* pA1 = pA0 + (size_t)64 * Cc;
    size_t boff = ((size_t)cb * 8 + mf0) * 512 + (size_t)lc0 * 8;
    const unsigned short* pG0 = PGseg + boff;
    const unsigned short* pG1 = pG0 + 2048;
    const unsigned short* pU0 = PUseg + boff;
    const unsigned short* pU1 = pU0 + 2048;
    const size_t bstep = (size_t)nct * 4096;

    f32x4 accG[4][4], accU[4][4];
#pragma unroll
    for (int m = 0; m < 4; m++)
#pragma unroll
        for (int n = 0; n < 4; n++) {
            accG[m][n] = (f32x4){0.f, 0.f, 0.f, 0.f};
            accU[m][n] = (f32x4){0.f, 0.f, 0.f, 0.f};
        }

    short8v av[2], gv[2], uv[2];
    av[0] = *reinterpret_cast<const short8v*>(pA0);
    av[1] = *reinterpret_cast<const short8v*>(pA1);
    gv[0] = *reinterpret_cast<const short8v*>(pG0);
    gv[1] = *reinterpret_cast<const short8v*>(pG1);
    uv[0] = *reinterpret_cast<const short8v*>(pU0);
    uv[1] = *reinterpret_cast<const short8v*>(pU1);
    pA0 += 32; pA1 += 32; pG0 += bstep; pG1 += bstep; pU0 += bstep; pU1 += bstep;

    const int nKt = Cc >> 5;                    // 32
    for (int kt = 0; kt < nKt; ++kt) {
        __syncthreads();
        *reinterpret_cast<short8v*>(&lds[(size_t)tid * 8]) = av[0];
        *reinterpret_cast<short8v*>(&lds[(size_t)(tid + 256) * 8]) = av[1];
        *reinterpret_cast<short8v*>(&lds[4096 + (size_t)tid * 8]) = gv[0];
        *reinterpret_cast<short8v*>(&lds[4096 + (size_t)(tid + 256) * 8]) = gv[1];
        *reinterpret_cast<short8v*>(&lds[8192 + (size_t)tid * 8]) = uv[0];
        *reinterpret_cast<short8v*>(&lds[8192 + (size_t)(tid + 256) * 8]) = uv[1];
        __syncthreads();
        if (kt + 1 < nKt) {
            av[0] = *reinterpret_cast<const short8v*>(pA0);
            av[1] = *reinterpret_cast<const short8v*>(pA1);
            gv[0] = *reinterpret_cast<const short8v*>(pG0);
            gv[1] = *reinterpret_cast<const short8v*>(pG1);
            uv[0] = *reinterpret_cast<const short8v*>(pU0);
            uv[1] = *reinterpret_cast<const short8v*>(pU1);
            pA0 += 32; pA1 += 32; pG0 += bstep; pG1 += bstep; pU0 += bstep; pU1 += bstep;
        }
        short8v afr[4];
#pragma unroll
        for (int m = 0; m < 4; m++)
            afr[m] = *reinterpret_cast<short8v*>(&lds[((wr * 4 + m) * 64 + lane) * 8]);
        {
            short8v gfr[4];
#pragma unroll
            for (int n = 0; n < 4; n++)
                gfr[n] = *reinterpret_cast<short8v*>(&lds[4096 + ((wc * 4 + n) * 64 + lane) * 8]);
#pragma unroll
            for (int m = 0; m < 4; m++)
#pragma unroll
                for (int n = 0; n < 4; n++)
                    accG[m][n] = __builtin_amdgcn_mfma_f32_16x16x32_bf16(
                        afr[m], gfr[n], accG[m][n], 0, 0, 0);
        }
        {
            short8v ufr[4];
#pragma unroll
            for (int n = 0; n < 4; n++)
                ufr[n] = *reinterpret_cast<short8v*>(&lds[8192 + ((wc * 4 + n) * 64 + lane) * 8]);
#pragma unroll
            for (int m = 0; m < 4; m++)
#pragma unroll
                for (int n = 0; n < 4; n++)
                    accU[m][n] = __builtin_amdgcn_mfma_f32_16x16x32_bf16(
                        afr[m], ufr[n], accU[m][n], 0, 0, 0);
        }
    }

    // epilogue: t = silu(g) * u
#pragma unroll
    for (int n = 0; n < 4; n++) {
        int col = cb * 128 + wc * 64 + n * 16 + c_;
#pragma unroll
        for (int m = 0; m < 4; m++) {
#pragma unroll
            for (int r = 0; r < 4; r++) {
                int row = rb + wr * 64 + m * 16 + g * 4 + r;
                float gval = accG[m][n][r], uval = accU[m][n][r];
                float t = gval / (1.f + __expf(-gval)) * uval;
                outp[(size_t)row * Ii + col] = f2bf(t);
            }
        }
    }
}

// ---------------------------------------------------------------------------
// proj combine: h(out) = x + bias[seg] + p0 + p1   (fp32 partials)
// ---------------------------------------------------------------------------
__global__ __launch_bounds__(256)
void combine_proj(const float* __restrict__ x, const float* __restrict__ bias,
                  const float* __restrict__ p, float* __restrict__ hb) {
    int i = blockIdx.x * 256 + threadIdx.x;     // float4 index
    int base = i * 4;
    int col = base % Cc;
    int n   = (base / Cc) % Nn;
    int seg = segof(n);
    float4 a = reinterpret_cast<const float4*>(x)[i];
    float4 b = *reinterpret_cast<const float4*>(&bias[(size_t)seg * Cc + col]);
    float4 p0 = reinterpret_cast<const float4*>(p)[i];
    float4 p1 = reinterpret_cast<const float4*>(p)[i + Mrows * Cc / 4];
    float4 r;
    r.x = a.x + b.x + p0.x + p1.x;
    r.y = a.y + b.y + p0.y + p1.y;
    r.z = a.z + b.z + p0.z + p1.z;
    r.w = a.w + b.w + p0.w + p1.w;
    reinterpret_cast<float4*>(hb)[i] = r;
}

// ---------------------------------------------------------------------------
// down combine: out = h(out) + sum_z bf2f(p_z)    (bf16 partials, NZ=4)
// ---------------------------------------------------------------------------
__global__ __launch_bounds__(256)
void combine_down4(const unsigned short* __restrict__ p,
                   float* __restrict__ out) {
    int i = blockIdx.x * 256 + threadIdx.x;     // 4-elem group
    float4 a = reinterpret_cast<const float4*>(out)[i];
#pragma unroll
    for (int z = 0; z < 4; z++) {
        ushort4 u = *reinterpret_cast<const ushort4*>(&p[(size_t)z * Mrows * Cc + i * 4]);
        a.x += bf2f(u.x); a.y += bf2f(u.y); a.z += bf2f(u.z); a.w += bf2f(u.w);
    }
    reinterpret_cast<float4*>(out)[i] = a;
}

// ---------------------------------------------------------------------------
// Split qkv(bf16) + per-head q/k RMSNorm + RoPE -> bf16 Q,K,V (bh, n, dh)
// ---------------------------------------------------------------------------
__global__ __launch_bounds__(256)
void split_rope(const unsigned short* __restrict__ qkv,
                const float* __restrict__ qn_w, const float* __restrict__ kn_w,
                const int* __restrict__ pos_ids, const int* __restrict__ tpos_ids,
                unsigned short* __restrict__ Q, unsigned short* __restrict__ K,
                unsigned short* __restrict__ V) {
    int row = blockIdx.x;   // b*N + n
    int b = row / Nn, n = row % Nn;
    int seg = segof(n);
    int lane = threadIdx.x & 63, wid = threadIdx.x >> 6;
    int pos = (n < Tt) ? tpos_ids[n] : pos_ids[n - Tt];
    int j = lane & 31;
    float ang = (float)pos * exp2f(-(float)j * (13.287712379549449f / 32.f));
    float cv = cosf(ang), sv = sinf(ang);
    float qw = qn_w[seg * DH + lane], kw = kn_w[seg * DH + lane];
    for (int h = wid; h < Hh; h += 4) {
        const unsigned short* base = qkv + (size_t)row * (3 * Cc) + h * DH + lane;
        float q = bf2f(base[0]), k = bf2f(base[Cc]), v = bf2f(base[2 * Cc]);
        float qs = q * q, ks = k * k;
#pragma unroll
        for (int off = 32; off; off >>= 1) {
            qs += __shfl_xor(qs, off, 64);
            ks += __shfl_xor(ks, off, 64);
        }
        q = q * rsqrtf(qs * (1.f / DH) + 1e-6f) * qw;
        k = k * rsqrtf(ks * (1.f / DH) + 1e-6f) * kw;
        float qp = __shfl_xor(q, 32, 64);
        float kp = __shfl_xor(k, 32, 64);
        float qo = q * cv + ((lane < 32) ? -qp * sv : qp * sv);
        float ko = k * cv + ((lane < 32) ? -kp * sv : kp * sv);
        size_t oidx = ((size_t)(b * Hh + h) * Nn + n) * DH + lane;
        Q[oidx] = f2bf(qo);
        K[oidx] = f2bf(ko);
        V[oidx] = f2bf(v);
    }
}

// ---------------------------------------------------------------------------
// MFMA flash attention (unchanged — verified)
// ---------------------------------------------------------------------------
__global__ __launch_bounds__(256)
void attn_mfma(const unsigned short* __restrict__ Qg,
               const unsigned short* __restrict__ Kg,
               const unsigned short* __restrict__ Vg,
               unsigned short* __restrict__ O) {
    __shared__ __align__(16) unsigned short k_lds[64 * 64];   // 8 KB
    __shared__ __align__(16) unsigned short vt_lds[64 * 64];  // 8 KB
    __shared__ __align__(16) unsigned short p_lds[4][16 * 64];// 8 KB

    int qt = blockIdx.x;
    int bh = blockIdx.y;
    int b = bh >> 4, h = bh & 15;
    int tid = threadIdx.x, lane = tid & 63, wid = tid >> 6;
    int g = lane >> 4, c = lane & 15;

    const size_t headoff = (size_t)bh * Nn * DH;
    int q0 = qt * 64;
    bool qtext = q0 < Tt;
    int qb = qtext ? 0 : (q0 - Tt) / BSz;

    int qrow_frag = q0 + wid * 16 + c;
    short8v aq[2];
#pragma unroll
    for (int kb = 0; kb < 2; kb++)
        aq[kb] = *reinterpret_cast<const short8v*>(
            &Qg[headoff + (size_t)qrow_frag * DH + kb * 32 + g * 8]);

    unsigned short* pbuf = &p_lds[wid][0];

    f32x4 o_[4];
#pragma unroll
    for (int nb = 0; nb < 4; nb++) o_[nb] = (f32x4){0.f, 0.f, 0.f, 0.f};
    float m_[4] = {-3.4e38f, -3.4e38f, -3.4e38f, -3.4e38f};
    float l_[4] = {0.f, 0.f, 0.f, 0.f};

    int tr = tid >> 2, tc = tid & 3;

    for (int kt = 0; kt < Nn / 64; kt++) {
        int kbase = kt * 64;
        bool vis, diag = false;
        if (qtext) {
            vis = (kbase <= q0);
            diag = (kbase == q0);
        } else if (kbase < Tt) {
            vis = true;
        } else {
            int kb = (kbase - Tt) / BSz;
            vis = (qb < L1) ? (kb <= qb)
                            : ((kb < L1 && qb - L1 > kb) || kb == qb);
        }
        if (!vis) continue;

        __syncthreads();
        {
            const unsigned short* ks = &Kg[headoff + (size_t)(kbase + tr) * DH];
            const unsigned short* vs = &Vg[headoff + (size_t)(kbase + tr) * DH];
#pragma unroll
            for (int i = 0; i < 2; i++) {
                int ch = tc + i * 4;
                short8v kv = *reinterpret_cast<const short8v*>(ks + ch * 8);
                int byte = (tr * 128 + ch * 16) ^ ((tr & 7) << 4);
                *reinterpret_cast<short8v*>((char*)k_lds + byte) = kv;
                short8v vv = *reinterpret_cast<const short8v*>(vs + ch * 8);
#pragma unroll
                for (int j = 0; j < 8; j++) {
                    int dh = ch * 8 + j;
                    int vbyte = (dh * 128 + tr * 2) ^ ((dh & 7) << 4);
                    *reinterpret_cast<unsigned short*>((char*)vt_lds + vbyte) =
                        (unsigned short)vv[j];
                }
            }
        }
        __syncthreads();

        f32x4 s_[4];
#pragma unroll
        for (int nb = 0; nb < 4; nb++) s_[nb] = (f32x4){0.f, 0.f, 0.f, 0.f};
#pragma unroll
        for (int nb = 0; nb < 4; nb++) {
            int kil = nb * 16 + c;
#pragma unroll
            for (int kb = 0; kb < 2; kb++) {
                int byte = (kil * 128 + kb * 64 + g * 16) ^ ((kil & 7) << 4);
                short8v bk = *reinterpret_cast<short8v*>((char*)k_lds + byte);
                s_[nb] = __builtin_amdgcn_mfma_f32_16x16x32_bf16(aq[kb], bk, s_[nb], 0, 0, 0);
            }
        }
#pragma unroll
        for (int nb = 0; nb < 4; nb++) {
#pragma unroll
            for (int r = 0; r < 4; r++) {
                float sv = s_[nb][r] * 0.125f;
                if (diag) {
                    int qrl = wid * 16 + g * 4 + r;
                    int kcl = nb * 16 + c;
                    if (qrl < kcl) sv = -3.4e38f;
                }
                s_[nb][r] = sv;
            }
        }
#pragma unroll
        for (int r = 0; r < 4; r++) {
            float mx = fmaxf(fmaxf(s_[0][r], s_[1][r]), fmaxf(s_[2][r], s_[3][r]));
#pragma unroll
            for (int off = 1; off <= 8; off <<= 1)
                mx = fmaxf(mx, __shfl_xor(mx, off, 64));
            float mn = fmaxf(m_[r], mx);
            float es = __expf(m_[r] - mn);
            m_[r] = mn;
            float pv[4];
            float rs = 0.f;
#pragma unroll
            for (int nb = 0; nb < 4; nb++) {
                pv[nb] = __expf(s_[nb][r] - mn);
                rs += pv[nb];
            }
#pragma unroll
            for (int off = 1; off <= 8; off <<= 1)
                rs += __shfl_xor(rs, off, 64);
            l_[r] = l_[r] * es + rs;
#pragma unroll
            for (int nb = 0; nb < 4; nb++) o_[nb][r] *= es;
            int qrl = g * 4 + r;
            int swz = (qrl & 7) << 4;
#pragma unroll
            for (int nb = 0; nb < 4; nb++) {
                int byte = (qrl * 128 + (nb * 16 + c) * 2) ^ swz;
                *reinterpret_cast<unsigned short*>((char*)pbuf + byte) = f2bf(pv[nb]);
            }
        }
        short8v aP[2];
#pragma unroll
        for (int kb = 0; kb < 2; kb++) {
            int byte = (c * 128 + kb * 64 + g * 16) ^ ((c & 7) << 4);
            aP[kb] = *reinterpret_cast<short8v*>((char*)pbuf + byte);
        }
#pragma unroll
        for (int nb = 0; nb < 4; nb++) {
            int dh = nb * 16 + c;
#pragma unroll
            for (int kb = 0; kb < 2; kb++) {
                int byte = (dh * 128 + kb * 64 + g * 16) ^ ((dh & 7) << 4);
                short8v bv = *reinterpret_cast<short8v*>((char*)vt_lds + byte);
                o_[nb] = __builtin_amdgcn_mfma_f32_16x16x32_bf16(aP[kb], bv, o_[nb], 0, 0, 0);
            }
        }
    }

    float inv_[4];
#pragma unroll
    for (int r = 0; r < 4; r++) inv_[r] = 1.f / l_[r];
#pragma unroll
    for (int nb = 0; nb < 4; nb++) {
        int col = h * DH + nb * 16 + c;
#pragma unroll
        for (int r = 0; r < 4; r++) {
            int row = q0 + wid * 16 + g * 4 + r;
            O[((size_t)b * Nn + row) * Cc + col] = f2bf(o_[nb][r] * inv_[r]);
        }
    }
}

// ---------------------------------------------------------------------------
// kernel_launch
// ---------------------------------------------------------------------------
extern "C" void kernel_launch(void* const* d_in, const int* in_sizes, int n_in,
                              void* d_out, int out_size, void* d_ws, size_t ws_size,
                              hipStream_t stream) {
    const float* x        = (const float*)d_in[0];
    const int*   pos_ids  = (const int*)d_in[1];
    const int*   tpos_ids = (const int*)d_in[2];
    const float* qkv_w    = (const float*)d_in[3];
    const float* qkv_b    = (const float*)d_in[4];
    const float* proj_w   = (const float*)d_in[5];
    const float* proj_b   = (const float*)d_in[6];
    const float* qn_w     = (const float*)d_in[7];
    const float* kn_w     = (const float*)d_in[8];
    const float* ln1_w    = (const float*)d_in[9];
    const float* ln2_w    = (const float*)d_in[10];
    const float* gate_w   = (const float*)d_in[11];
    const float* up_w     = (const float*)d_in[12];
    const float* down_w   = (const float*)d_in[13];
    float* out = (float*)d_out;                 // also used as h buffer
    char*  wsb = (char*)d_ws;

    // workspace regions (bytes), peak 76.5 MB
    unsigned short* WA  = (unsigned short*)(wsb);               // 25.2 MB (qkv_p/proj_p/gate_p/down_p)
    unsigned short* WB  = (unsigned short*)(wsb + 25165824);    // 25.2 MB (qkvb / up_p / down partials)
    unsigned short* Tb  = (unsigned short*)(wsb + 50331648);    // 21.0 MB (QKV / proj partials / t)
    unsigned short* P3  = (unsigned short*)(wsb + 71303168);    //  5.2 MB (xn / obf / y)
    unsigned short* Qbf = Tb;
    unsigned short* Kbf = Tb + 2621440;
    unsigned short* Vbf = Tb + 5242880;

    // 1. xn = RMS(x, ln1) -> bf16 (P3)
    rms_bf16<<<Mrows, 256, 0, stream>>>(x, ln1_w, P3);
    // 2. pack qkv -> WA; qkv GEMM -> qkvb (WB)   (480 blocks)
    pack_w<<<4608, 256, 0, stream>>>(qkv_w, WA, Cc, 3 * Cc);
    gemm128r<1, true, 1><<<dim3(Mrows / 128, 24), 256, 0, stream>>>(
        P3, WA, qkv_b, WB, Cc, 3 * Cc);
    // 3. split + q/k RMS + RoPE -> Q,K,V (Tb)
    split_rope<<<Mrows, 256, 0, stream>>>(WB, qn_w, kn_w, pos_ids, tpos_ids,
                                          Qbf, Kbf, Vbf);
    // 4. attention -> obf (P3)
    attn_mfma<<<dim3(Nn / 64, Bb * Hh), 256, 0, stream>>>(Qbf, Kbf, Vbf, P3);
    // 5. proj split-K=2 -> fp32 partials (Tb); combine -> h in out  (320 blocks)
    pack_w<<<1536, 256, 0, stream>>>(proj_w, WA, Cc, Cc);
    gemm128r<0, false, 2><<<dim3(Mrows / 128, 8, 2), 256, 0, stream>>>(
        P3, WA, nullptr, (float*)Tb, Cc, Cc);
    combine_proj<<<Mrows * Cc / 1024, 256, 0, stream>>>(x, proj_b, (float*)Tb, out);
    // 6. y = RMS(h, ln2) -> bf16 (P3)
    rms_bf16<<<Mrows, 256, 0, stream>>>(out, ln2_w, P3);
    // 7. fused: t = silu(y@gate) * (y@up) -> Tb   (640 blocks)
    pack_w<<<6144, 256, 0, stream>>>(gate_w, WA, Cc, Ii);
    pack_w<<<6144, 256, 0, stream>>>(up_w, WB, Cc, Ii);
    gemm_gu<<<dim3(Mrows / 128, 32), 256, 0, stream>>>(P3, WA, WB, Tb);
    // 8. down split-K=4 -> bf16 partials (WB); out = h + sum(p_z)  (640 blocks)
    pack_w<<<6144, 256, 0, stream>>>(down_w, WA, Ii, Cc);
    gemm128r<1, false, 4><<<dim3(Mrows / 128, 8, 4), 256, 0, stream>>>(
        Tb, WA, nullptr, WB, Ii, Cc);
    combine_down4<<<Mrows * Cc / 1024, 256, 0, stream>>>(WB, out);
}